// Round 19
// baseline (227.737 us; speedup 1.0000x reference)
//
#include <hip/hip_runtime.h>
#include <hip/hip_bf16.h>

#define S_LEN 4096
#define EMB 768
#define NHEAD 8
#define HDIM 96

typedef short bf16x8 __attribute__((ext_vector_type(8)));
typedef float f32x4 __attribute__((ext_vector_type(4)));
typedef float f32x16 __attribute__((ext_vector_type(16)));

__device__ __forceinline__ short f2bf(float x) {
  union { float f; unsigned u; } v; v.f = x;
  unsigned r = v.u + 0x7fffu + ((v.u >> 16) & 1u);   // round-to-nearest-even
  return (short)(r >> 16);
}

__device__ __forceinline__ short f2bfh(float x) {
  union { __hip_bfloat16 h; short s; } u;
  u.h = __float2bfloat16(x);
  return u.s;
}

#define GLOAD_LDS16(gp, lp)                                              \
  __builtin_amdgcn_global_load_lds(                                      \
      (const __attribute__((address_space(1))) unsigned int*)(gp),       \
      (__attribute__((address_space(3))) unsigned int*)(lp), 16, 0, 0)

// ---------- fused prep (unchanged from r16-r18) ----------
// blocks [0,288):      W -> bf16.
// blocks [288,1312):   K half of KVT tile (12KB): unit u = c*128 + ksub*64 + hi*32 + l31
//                      holds K[32ksub+l31][16c+8hi..+7] -> QK A-frag read lane-linear.
// blocks [1312,2336):  V half (12KB): lane-linear sigma layout (sigma = swap key bits
//                      2<->3, matches 32x32 MFMA C/D slots -> P packs identity).
__global__ __launch_bounds__(256) void prep_kernel(const float* __restrict__ K,
                                                   const float* __restrict__ W,
                                                   const float* __restrict__ V,
                                                   short* __restrict__ KVT,
                                                   short* __restrict__ Wb) {
  __shared__ short tlbuf[6656];
  int b = blockIdx.x;
  int tid = threadIdx.x;
  if (b < 288) {
    int t = b * 256 + tid;
    size_t off = (size_t)t * 8;
    float4 a = *(const float4*)(W + off);
    float4 bq = *(const float4*)(W + off + 4);
    bf16x8 r;
    r[0]=f2bf(a.x);  r[1]=f2bf(a.y);  r[2]=f2bf(a.z);  r[3]=f2bf(a.w);
    r[4]=f2bf(bq.x); r[5]=f2bf(bq.y); r[6]=f2bf(bq.z); r[7]=f2bf(bq.w);
    *(bf16x8*)(Wb + off) = r;
    return;
  }
  if (b < 1312) {
    int bb = b - 288;
    int n = bb >> 9, h = (bb >> 6) & 7, st = bb & 63;
    int s0 = st * 64;
    const float* kp = K + ((size_t)(n * S_LEN + s0)) * EMB + h * HDIM;
    #pragma unroll
    for (int k = 0; k < 6; ++k) {
      int idx = k * 256 + tid;
      int fidx = idx * 4;
      int s = fidx / 96, d = fidx % 96;
      float4 a = *(const float4*)(kp + (size_t)s * EMB + d);
      short* t4 = &tlbuf[s * 104 + d];
      t4[0] = f2bf(a.x); t4[1] = f2bf(a.y); t4[2] = f2bf(a.z); t4[3] = f2bf(a.w);
    }
    __syncthreads();
    short* KVp = KVT + ((size_t)((n * NHEAD + h) * 64 + st)) * 12288;
    #pragma unroll
    for (int i = 0; i < 3; ++i) {
      int u = i * 256 + tid;
      int c = u >> 7, rem = u & 127;
      int ksub = (rem >> 6) & 1, hi2 = (rem >> 5) & 1, l31 = rem & 31;
      int key = ksub * 32 + l31;
      int db = c * 16 + hi2 * 8;
      short4 lo = *(const short4*)&tlbuf[key * 104 + db];
      short4 hi4 = *(const short4*)&tlbuf[key * 104 + db + 4];
      bf16x8 r;
      r[0]=lo.x; r[1]=lo.y; r[2]=lo.z; r[3]=lo.w;
      r[4]=hi4.x; r[5]=hi4.y; r[6]=hi4.z; r[7]=hi4.w;
      *(bf16x8*)(KVp + (size_t)u * 8) = r;
    }
    return;
  }
  int bb = b - 1312;
  int n = bb >> 9, h = (bb >> 6) & 7, st = bb & 63;
  int s0 = st * 64;
  const float* vp = V + ((size_t)(n * S_LEN + s0)) * EMB + h * HDIM;
  #pragma unroll
  for (int k = 0; k < 6; ++k) {
    int idx = k * 256 + tid;
    int fidx = idx * 4;
    int s = fidx / 96, d = fidx % 96;
    float4 a = *(const float4*)(vp + (size_t)s * EMB + d);
    tlbuf[(d + 0) * 68 + s] = f2bf(a.x);
    tlbuf[(d + 1) * 68 + s] = f2bf(a.y);
    tlbuf[(d + 2) * 68 + s] = f2bf(a.z);
    tlbuf[(d + 3) * 68 + s] = f2bf(a.w);
  }
  __syncthreads();
  short* KVp = KVT + ((size_t)((n * NHEAD + h) * 64 + st)) * 12288 + 6144;
  #pragma unroll
  for (int i = 0; i < 3; ++i) {
    int u = i * 256 + tid;
    int slice = u / 192;
    int rem = u - slice * 192;
    int dt = rem >> 6, hi2 = (rem >> 5) & 1, d5 = rem & 31;
    int d = dt * 32 + d5;
    int kb = 16 * slice + 4 * hi2;
    short4 lo = *(const short4*)&tlbuf[d * 68 + kb];
    short4 hi4 = *(const short4*)&tlbuf[d * 68 + kb + 8];
    bf16x8 r;
    r[0]=lo.x; r[1]=lo.y; r[2]=lo.z; r[3]=lo.w;
    r[4]=hi4.x; r[5]=hi4.y; r[6]=hi4.z; r[7]=hi4.w;
    *(bf16x8*)(KVp + (size_t)u * 8) = r;
  }
}

// ---------- flash attention: no split-K, q-tile 64, 2 waves x 32 q, 4 blocks/CU ----------
// r15-r18 showed attn pinned ~115us across occupancy/conflict/LDS-traffic changes ->
// structural per-iter path; split-K's ~25us of overhead (combine kernel, partial
// traffic, extra launch) buys nothing. This round: grid = 16 (n,h) x 64 q-tiles = 1024
// blocks of 128 thr; 36KB LDS (K sbuf + V dbuf) -> 4 blocks/CU all co-resident, zero
// tail, 2 waves/SIMD. Direct Xb epilogue (l col-layout -> LDS broadcast). Iter:
// QK(kbuf) | barrier1 | stage K(t+1)->kbuf, V(t+1)->vbuf^1 | exp/pack/PV(vbuf[cur]) |
// barrier2 (drains staging under softmax+PV). All LDS reads lane-linear, conflict-free.
__global__ __launch_bounds__(128, 4) void attn_kernel(const float* __restrict__ Q,
                                                      const short* __restrict__ KVT,
                                                      short* __restrict__ Xb) {
  __shared__ __align__(16) char smem[36864];   // kbuf 12KB @0 | vbuf[2] 12KB @12288
  constexpr int ITERS = S_LEN / 64;
  int L = blockIdx.x;
  int h = L & 7, j = L >> 3;
  int n = j >> 6, qt = j & 63;
  int q0 = qt * 64;
  int tid = threadIdx.x;
  int w = tid >> 6, lane = tid & 63, l31 = lane & 31, hi = lane >> 5;

  const float kAdj = 0.14724512f;  // (1/sqrt(96)) * log2(e), folded into Q
  bf16x8 qf[6];
  {
    const float* qp = Q + ((size_t)(n * S_LEN + q0 + w * 32 + l31)) * EMB + h * HDIM + 8 * hi;
    #pragma unroll
    for (int c = 0; c < 6; ++c) {
      float4 a = *(const float4*)(qp + 16 * c);
      float4 bq = *(const float4*)(qp + 16 * c + 4);
      bf16x8 r;
      r[0]=f2bf(a.x*kAdj);  r[1]=f2bf(a.y*kAdj);  r[2]=f2bf(a.z*kAdj);  r[3]=f2bf(a.w*kAdj);
      r[4]=f2bf(bq.x*kAdj); r[5]=f2bf(bq.y*kAdj); r[6]=f2bf(bq.z*kAdj); r[7]=f2bf(bq.w*kAdj);
      qf[c] = r;
    }
  }

  // staging: wave w covers K units w*6..w*6+5 and V units w*6..w*6+5 (12 gload16/wave)
  const short* gKV = KVT + (size_t)(n * NHEAD + h) * 64 * 12288
                        + (size_t)(w * 6) * 512 + lane * 8;
  char* kbuf = smem;
  char* vbuf = smem + 12288;
  char* kdst = kbuf + w * 6144;
  char* vdst0 = vbuf + w * 6144;

  // prologue: stage K(0) + V(0)
  #pragma unroll
  for (int i = 0; i < 6; ++i) {
    GLOAD_LDS16(gKV + i * 512, kdst + i * 1024);
    GLOAD_LDS16(gKV + 6144 + i * 512, vdst0 + i * 1024);
  }
  __syncthreads();

  f32x16 o[3];
  #pragma unroll
  for (int dt = 0; dt < 3; ++dt) o[dt] = (f32x16){};
  float tsl = 0.f;

  int cur = 0;
  #pragma unroll 1
  for (int t = 0; t < ITERS; ++t) {
    // ---- QK^T both 32-key subtiles (12 independent ds_read+MFMA) ----
    f32x16 s0 = (f32x16){}, s1 = (f32x16){};
    __builtin_amdgcn_s_setprio(1);
    #pragma unroll
    for (int c = 0; c < 6; ++c) {
      bf16x8 kf = *(const bf16x8*)(kbuf + c * 2048 + lane * 16);
      s0 = __builtin_amdgcn_mfma_f32_32x32x16_bf16(kf, qf[c], s0, 0, 0, 0);
    }
    #pragma unroll
    for (int c = 0; c < 6; ++c) {
      bf16x8 kf = *(const bf16x8*)(kbuf + c * 2048 + 1024 + lane * 16);
      s1 = __builtin_amdgcn_mfma_f32_32x32x16_bf16(kf, qf[c], s1, 0, 0, 0);
    }
    __builtin_amdgcn_s_setprio(0);
    __syncthreads();               // all K(t) reads complete; kbuf overwrite safe

    if (t < ITERS - 1) {           // stage K(t+1) -> kbuf, V(t+1) -> vbuf^1
      const short* src = gKV + (size_t)(t + 1) * 12288;
      char* vd = vbuf + (cur ^ 1) * 12288 + w * 6144;
      #pragma unroll
      for (int i = 0; i < 6; ++i) {
        GLOAD_LDS16(src + i * 512, kdst + i * 1024);
        GLOAD_LDS16(src + 6144 + i * 512, vd + i * 1024);
      }
    }

    // ---- P = 2^score; pairwise-tree row-sum (col-layout) ----
    #pragma unroll
    for (int r = 0; r < 16; ++r) s0[r] = __builtin_amdgcn_exp2f(s0[r]);
    #pragma unroll
    for (int r = 0; r < 16; ++r) s1[r] = __builtin_amdgcn_exp2f(s1[r]);
    {
      float a0 = (s0[0]+s0[1]) + (s0[2]+s0[3]), a1 = (s0[4]+s0[5]) + (s0[6]+s0[7]);
      float a2 = (s0[8]+s0[9]) + (s0[10]+s0[11]), a3 = (s0[12]+s0[13]) + (s0[14]+s0[15]);
      float b0 = (s1[0]+s1[1]) + (s1[2]+s1[3]), b1 = (s1[4]+s1[5]) + (s1[6]+s1[7]);
      float b2 = (s1[8]+s1[9]) + (s1[10]+s1[11]), b3 = (s1[12]+s1[13]) + (s1[14]+s1[15]);
      tsl += ((a0+a1) + (a2+a3)) + ((b0+b1) + (b2+b3));
    }

    // ---- pack (identity) + PV per 16-key slice; V(t) from vbuf[cur] ----
    const char* vbl = vbuf + cur * 12288;
    #pragma unroll
    for (int ksub = 0; ksub < 2; ++ksub) {
      const f32x16& s = ksub ? s1 : s0;
      #pragma unroll
      for (int ks = 0; ks < 2; ++ks) {
        unsigned d0, d1, d2, d3;
        asm("v_cvt_pk_bf16_f32 %0, %1, %2" : "=v"(d0) : "v"(s[8*ks+0]), "v"(s[8*ks+1]));
        asm("v_cvt_pk_bf16_f32 %0, %1, %2" : "=v"(d1) : "v"(s[8*ks+2]), "v"(s[8*ks+3]));
        asm("v_cvt_pk_bf16_f32 %0, %1, %2" : "=v"(d2) : "v"(s[8*ks+4]), "v"(s[8*ks+5]));
        asm("v_cvt_pk_bf16_f32 %0, %1, %2" : "=v"(d3) : "v"(s[8*ks+6]), "v"(s[8*ks+7]));
        union { unsigned u[4]; bf16x8 v; } pu;
        pu.u[0] = d0; pu.u[1] = d1; pu.u[2] = d2; pu.u[3] = d3;
        int slice = 2 * ksub + ks;
        __builtin_amdgcn_s_setprio(1);
        #pragma unroll
        for (int dt = 0; dt < 3; ++dt) {
          bf16x8 vf = *(const bf16x8*)(vbl + (slice * 3 + dt) * 1024 + hi * 512 + l31 * 16);
          o[dt] = __builtin_amdgcn_mfma_f32_32x32x16_bf16(pu.v, vf, o[dt], 0, 0, 0);
        }
        __builtin_amdgcn_s_setprio(0);
      }
    }
    __syncthreads();     // drains K(t+1)/V(t+1) staging (hidden under softmax+PV)
    cur ^= 1;
  }

  // ---- epilogue: l (col-layout, row = l31) -> LDS broadcast -> row-layout normalize ----
  float lcol = tsl + __shfl_xor(tsl, 32, 64);
  __syncthreads();
  float* bcf = (float*)smem;
  if (hi == 0) bcf[w * 32 + l31] = 1.0f / lcol;
  __syncthreads();
  #pragma unroll
  for (int p = 0; p < 4; ++p) {
    #pragma unroll
    for (int jj = 0; jj < 4; ++jj) {
      int qr = 8 * p + 4 * hi + jj;
      float iv = bcf[w * 32 + qr];
      short* xp = Xb + ((size_t)(n * S_LEN + q0 + w * 32 + qr)) * EMB + h * HDIM + l31;
      xp[0]  = f2bfh(o[0][4*p+jj] * iv);
      xp[32] = f2bfh(o[1][4*p+jj] * iv);
      xp[64] = f2bfh(o[2][4*p+jj] * iv);
    }
  }
}

// ---------- FC: out[m][j] = sum_k X[m][k] * W[j][k] + b[j] ----------
__global__ __launch_bounds__(256) void fc_kernel(const short* __restrict__ Xb,
                                                 const short* __restrict__ Wb,
                                                 const float* __restrict__ bias,
                                                 float* __restrict__ out) {
  int m0 = blockIdx.x * 64, j0 = blockIdx.y * 64;
  int tid = threadIdx.x;
  int w = tid >> 6, lane = tid & 63, lr = lane & 15, lg = lane >> 4;
  f32x4 acc[4];
  #pragma unroll
  for (int jt = 0; jt < 4; ++jt) acc[jt] = (f32x4){0.f, 0.f, 0.f, 0.f};
  const short* xp = Xb + (size_t)(m0 + w * 16 + lr) * EMB + 8 * lg;
  const short* wp = Wb + (size_t)(j0 + lr) * EMB + 8 * lg;
  #pragma unroll 1
  for (int kt = 0; kt < 24; ++kt) {
    bf16x8 a = *(const bf16x8*)(xp + kt * 32);
    #pragma unroll
    for (int jt = 0; jt < 4; ++jt) {
      bf16x8 bw = *(const bf16x8*)(wp + (size_t)(jt * 16) * EMB + kt * 32);
      acc[jt] = __builtin_amdgcn_mfma_f32_16x16x32_bf16(a, bw, acc[jt], 0, 0, 0);
    }
  }
  #pragma unroll
  for (int jt = 0; jt < 4; ++jt) {
    float bb = bias[j0 + jt * 16 + lr];
    #pragma unroll
    for (int i = 0; i < 4; ++i)
      out[(size_t)(m0 + w * 16 + 4 * lg + i) * EMB + j0 + jt * 16 + lr] = acc[jt][i] + bb;
  }
}

extern "C" void kernel_launch(void* const* d_in, const int* in_sizes, int n_in,
                              void* d_out, int out_size, void* d_ws, size_t ws_size,
                              hipStream_t stream) {
  (void)in_sizes; (void)n_in; (void)out_size; (void)ws_size;
  const float* V = (const float*)d_in[0];
  const float* K = (const float*)d_in[1];
  const float* Q = (const float*)d_in[2];
  const float* W = (const float*)d_in[3];
  const float* B = (const float*)d_in[4];
  float* out = (float*)d_out;
  // ws (shorts): KVT[12582912] | Wb[589824] | Xb[6291456]
  short* KVT = (short*)d_ws;
  short* Wb  = KVT + 12582912;
  short* Xb  = Wb + 589824;
  prep_kernel<<<2336, 256, 0, stream>>>(K, W, V, KVT, Wb);
  attn_kernel<<<1024, 128, 0, stream>>>(Q, KVT, Xb);
  fc_kernel<<<dim3(128, 12), 256, 0, stream>>>(Xb, Wb, B, out);
}

// Round 20
// 210.369 us; speedup vs baseline: 1.0826x; 1.0826x over previous
//
#include <hip/hip_runtime.h>
#include <hip/hip_bf16.h>

#define S_LEN 4096
#define EMB 768
#define NHEAD 8
#define HDIM 96

typedef short bf16x8 __attribute__((ext_vector_type(8)));
typedef float f32x4 __attribute__((ext_vector_type(4)));
typedef float f32x16 __attribute__((ext_vector_type(16)));

__device__ __forceinline__ short f2bf(float x) {
  union { float f; unsigned u; } v; v.f = x;
  unsigned r = v.u + 0x7fffu + ((v.u >> 16) & 1u);   // round-to-nearest-even
  return (short)(r >> 16);
}

__device__ __forceinline__ short f2bfh(float x) {
  union { __hip_bfloat16 h; short s; } u;
  u.h = __float2bfloat16(x);
  return u.s;
}

__device__ __forceinline__ float bf2f(short s) {
  union { unsigned u; float f; } v;
  v.u = ((unsigned)(unsigned short)s) << 16;
  return v.f;
}

#define GLOAD_LDS16(gp, lp)                                              \
  __builtin_amdgcn_global_load_lds(                                      \
      (const __attribute__((address_space(1))) unsigned int*)(gp),       \
      (__attribute__((address_space(3))) unsigned int*)(lp), 16, 0, 0)

// ---------- fused prep (unchanged from r16-r18) ----------
__global__ __launch_bounds__(256) void prep_kernel(const float* __restrict__ K,
                                                   const float* __restrict__ W,
                                                   const float* __restrict__ V,
                                                   short* __restrict__ KVT,
                                                   short* __restrict__ Wb) {
  __shared__ short tlbuf[6656];
  int b = blockIdx.x;
  int tid = threadIdx.x;
  if (b < 288) {
    int t = b * 256 + tid;
    size_t off = (size_t)t * 8;
    float4 a = *(const float4*)(W + off);
    float4 bq = *(const float4*)(W + off + 4);
    bf16x8 r;
    r[0]=f2bf(a.x);  r[1]=f2bf(a.y);  r[2]=f2bf(a.z);  r[3]=f2bf(a.w);
    r[4]=f2bf(bq.x); r[5]=f2bf(bq.y); r[6]=f2bf(bq.z); r[7]=f2bf(bq.w);
    *(bf16x8*)(Wb + off) = r;
    return;
  }
  if (b < 1312) {
    // K tile: unit u = c*128 + ksub*64 + hi*32 + l31 <- K[32ksub+l31][16c+8hi..+7]
    int bb = b - 288;
    int n = bb >> 9, h = (bb >> 6) & 7, st = bb & 63;
    int s0 = st * 64;
    const float* kp = K + ((size_t)(n * S_LEN + s0)) * EMB + h * HDIM;
    #pragma unroll
    for (int k = 0; k < 6; ++k) {
      int idx = k * 256 + tid;
      int fidx = idx * 4;
      int s = fidx / 96, d = fidx % 96;
      float4 a = *(const float4*)(kp + (size_t)s * EMB + d);
      short* t4 = &tlbuf[s * 104 + d];
      t4[0] = f2bf(a.x); t4[1] = f2bf(a.y); t4[2] = f2bf(a.z); t4[3] = f2bf(a.w);
    }
    __syncthreads();
    short* KVp = KVT + ((size_t)((n * NHEAD + h) * 64 + st)) * 12288;
    #pragma unroll
    for (int i = 0; i < 3; ++i) {
      int u = i * 256 + tid;
      int c = u >> 7, rem = u & 127;
      int ksub = (rem >> 6) & 1, hi2 = (rem >> 5) & 1, l31 = rem & 31;
      int key = ksub * 32 + l31;
      int db = c * 16 + hi2 * 8;
      short4 lo = *(const short4*)&tlbuf[key * 104 + db];
      short4 hi4 = *(const short4*)&tlbuf[key * 104 + db + 4];
      bf16x8 r;
      r[0]=lo.x; r[1]=lo.y; r[2]=lo.z; r[3]=lo.w;
      r[4]=hi4.x; r[5]=hi4.y; r[6]=hi4.z; r[7]=hi4.w;
      *(bf16x8*)(KVp + (size_t)u * 8) = r;
    }
    return;
  }
  // V tile: lane-linear sigma layout (sigma = swap key bits 2<->3)
  int bb = b - 1312;
  int n = bb >> 9, h = (bb >> 6) & 7, st = bb & 63;
  int s0 = st * 64;
  const float* vp = V + ((size_t)(n * S_LEN + s0)) * EMB + h * HDIM;
  #pragma unroll
  for (int k = 0; k < 6; ++k) {
    int idx = k * 256 + tid;
    int fidx = idx * 4;
    int s = fidx / 96, d = fidx % 96;
    float4 a = *(const float4*)(vp + (size_t)s * EMB + d);
    tlbuf[(d + 0) * 68 + s] = f2bf(a.x);
    tlbuf[(d + 1) * 68 + s] = f2bf(a.y);
    tlbuf[(d + 2) * 68 + s] = f2bf(a.z);
    tlbuf[(d + 3) * 68 + s] = f2bf(a.w);
  }
  __syncthreads();
  short* KVp = KVT + ((size_t)((n * NHEAD + h) * 64 + st)) * 12288 + 6144;
  #pragma unroll
  for (int i = 0; i < 3; ++i) {
    int u = i * 256 + tid;
    int slice = u / 192;
    int rem = u - slice * 192;
    int dt = rem >> 6, hi2 = (rem >> 5) & 1, d5 = rem & 31;
    int d = dt * 32 + d5;
    int kb = 16 * slice + 4 * hi2;
    short4 lo = *(const short4*)&tlbuf[d * 68 + kb];
    short4 hi4 = *(const short4*)&tlbuf[d * 68 + kb + 8];
    bf16x8 r;
    r[0]=lo.x; r[1]=lo.y; r[2]=lo.z; r[3]=lo.w;
    r[4]=hi4.x; r[5]=hi4.y; r[6]=hi4.z; r[7]=hi4.w;
    *(bf16x8*)(KVp + (size_t)u * 8) = r;
  }
}

// ---------- flash attention: r18 structure (64 q/wave, split-K x2) + bf16 partials
//            + V-stage hoisted to iter top (full-iter latency slack) ----------
// Block = 128 thr = 2 waves x 64 q-rows; grid = NKG*512; 36KB LDS (K sbuf + V dbuf).
// Iter: stage V(t+1)->vbuf^1 | QK(kbuf) | barrier1 | stage K(t+1)->kbuf |
// exp/pack/PV(vbuf[cur]) | barrier2 (drains staging). Fixed-max softmax -> split-K
// additive: O = sum O_kg / sum l_kg; partials stored bf16 (Xb is bf16 anyway).
template<int NKG>
__global__ __launch_bounds__(128, 2) void attn_kernel(const float* __restrict__ Q,
                                                      const short* __restrict__ KVT,
                                                      short* __restrict__ Xb,
                                                      short* __restrict__ Op,
                                                      float* __restrict__ lp) {
  __shared__ __align__(16) char smem[36864];   // kbuf 12KB @0 | vbuf[2] 12KB @12288
  constexpr int ITERS = S_LEN / NKG / 64;
  int L = blockIdx.x;
  int bb = L & 511;
  int kg = L >> 9;
  int h = bb & 7, j = bb >> 3;
  int n = j >> 5, qt = j & 31;
  int q0 = qt * 128;
  int tid = threadIdx.x;
  int w = tid >> 6, lane = tid & 63, l31 = lane & 31, hi = lane >> 5;

  const float kAdj = 0.14724512f;  // (1/sqrt(96)) * log2(e), folded into Q
  bf16x8 qfa[6], qfb[6];
  #pragma unroll
  for (int sub = 0; sub < 2; ++sub) {
    const float* qp = Q + ((size_t)(n * S_LEN + q0 + w * 64 + sub * 32 + l31)) * EMB
                        + h * HDIM + 8 * hi;
    #pragma unroll
    for (int c = 0; c < 6; ++c) {
      float4 a = *(const float4*)(qp + 16 * c);
      float4 bq = *(const float4*)(qp + 16 * c + 4);
      bf16x8 r;
      r[0]=f2bf(a.x*kAdj);  r[1]=f2bf(a.y*kAdj);  r[2]=f2bf(a.z*kAdj);  r[3]=f2bf(a.w*kAdj);
      r[4]=f2bf(bq.x*kAdj); r[5]=f2bf(bq.y*kAdj); r[6]=f2bf(bq.z*kAdj); r[7]=f2bf(bq.w*kAdj);
      if (sub == 0) qfa[c] = r; else qfb[c] = r;
    }
  }

  const short* gKV = KVT + ((size_t)((n * NHEAD + h) * 64 + kg * ITERS)) * 12288
                        + (size_t)(w * 6) * 512 + lane * 8;
  char* kbuf = smem;
  char* vbuf = smem + 12288;
  char* kdst = kbuf + w * 6144;
  char* vdst0 = vbuf + w * 6144;

  // prologue: stage K(0) + V(0)
  #pragma unroll
  for (int i = 0; i < 6; ++i) {
    GLOAD_LDS16(gKV + i * 512, kdst + i * 1024);
    GLOAD_LDS16(gKV + 6144 + i * 512, vdst0 + i * 1024);
  }
  __syncthreads();

  f32x16 oa[3], ob[3];
  #pragma unroll
  for (int dt = 0; dt < 3; ++dt) { oa[dt] = (f32x16){}; ob[dt] = (f32x16){}; }
  float tsa = 0.f, tsb = 0.f;

  int cur = 0;
  #pragma unroll 1
  for (int t = 0; t < ITERS; ++t) {
    // ---- stage V(t+1) -> vbuf^1 EARLY (vbuf^1 free since barrier2 of t-1) ----
    if (t < ITERS - 1) {
      const short* src = gKV + (size_t)(t + 1) * 12288;
      char* vd = vbuf + (cur ^ 1) * 12288 + w * 6144;
      #pragma unroll
      for (int i = 0; i < 6; ++i)
        GLOAD_LDS16(src + 6144 + i * 512, vd + i * 1024);
    }

    // ---- QK^T: 4 independent chains (2 key-subtiles x 2 q-subtiles), K read once ----
    f32x16 s0a = (f32x16){}, s1a = (f32x16){}, s0b = (f32x16){}, s1b = (f32x16){};
    __builtin_amdgcn_s_setprio(1);
    #pragma unroll
    for (int c = 0; c < 6; ++c) {
      bf16x8 kf0 = *(const bf16x8*)(kbuf + c * 2048 + lane * 16);
      bf16x8 kf1 = *(const bf16x8*)(kbuf + c * 2048 + 1024 + lane * 16);
      s0a = __builtin_amdgcn_mfma_f32_32x32x16_bf16(kf0, qfa[c], s0a, 0, 0, 0);
      s0b = __builtin_amdgcn_mfma_f32_32x32x16_bf16(kf0, qfb[c], s0b, 0, 0, 0);
      s1a = __builtin_amdgcn_mfma_f32_32x32x16_bf16(kf1, qfa[c], s1a, 0, 0, 0);
      s1b = __builtin_amdgcn_mfma_f32_32x32x16_bf16(kf1, qfb[c], s1b, 0, 0, 0);
    }
    __builtin_amdgcn_s_setprio(0);
    __syncthreads();               // all K(t) reads complete; kbuf overwrite safe

    if (t < ITERS - 1) {           // stage K(t+1) -> kbuf
      const short* src = gKV + (size_t)(t + 1) * 12288;
      #pragma unroll
      for (int i = 0; i < 6; ++i)
        GLOAD_LDS16(src + i * 512, kdst + i * 1024);
    }

    // ---- P = 2^score; pairwise-tree row-sums ----
    #pragma unroll
    for (int r = 0; r < 16; ++r) s0a[r] = __builtin_amdgcn_exp2f(s0a[r]);
    #pragma unroll
    for (int r = 0; r < 16; ++r) s1a[r] = __builtin_amdgcn_exp2f(s1a[r]);
    #pragma unroll
    for (int r = 0; r < 16; ++r) s0b[r] = __builtin_amdgcn_exp2f(s0b[r]);
    #pragma unroll
    for (int r = 0; r < 16; ++r) s1b[r] = __builtin_amdgcn_exp2f(s1b[r]);
    {
      float a0 = (s0a[0]+s0a[1])+(s0a[2]+s0a[3]), a1 = (s0a[4]+s0a[5])+(s0a[6]+s0a[7]);
      float a2 = (s0a[8]+s0a[9])+(s0a[10]+s0a[11]), a3 = (s0a[12]+s0a[13])+(s0a[14]+s0a[15]);
      float b0 = (s1a[0]+s1a[1])+(s1a[2]+s1a[3]), b1 = (s1a[4]+s1a[5])+(s1a[6]+s1a[7]);
      float b2 = (s1a[8]+s1a[9])+(s1a[10]+s1a[11]), b3 = (s1a[12]+s1a[13])+(s1a[14]+s1a[15]);
      tsa += ((a0+a1)+(a2+a3)) + ((b0+b1)+(b2+b3));
      float c0 = (s0b[0]+s0b[1])+(s0b[2]+s0b[3]), c1 = (s0b[4]+s0b[5])+(s0b[6]+s0b[7]);
      float c2 = (s0b[8]+s0b[9])+(s0b[10]+s0b[11]), c3 = (s0b[12]+s0b[13])+(s0b[14]+s0b[15]);
      float d0_ = (s1b[0]+s1b[1])+(s1b[2]+s1b[3]), d1_ = (s1b[4]+s1b[5])+(s1b[6]+s1b[7]);
      float d2_ = (s1b[8]+s1b[9])+(s1b[10]+s1b[11]), d3_ = (s1b[12]+s1b[13])+(s1b[14]+s1b[15]);
      tsb += ((c0+c1)+(c2+c3)) + ((d0_+d1_)+(d2_+d3_));
    }

    // ---- pack (identity) + PV; V fragment read once serves both q-subtiles ----
    const char* vbl = vbuf + cur * 12288;
    #pragma unroll
    for (int ksub = 0; ksub < 2; ++ksub) {
      const f32x16& sa = ksub ? s1a : s0a;
      const f32x16& sb = ksub ? s1b : s0b;
      #pragma unroll
      for (int ks = 0; ks < 2; ++ks) {
        unsigned a0, a1, a2, a3, b0, b1, b2, b3;
        asm("v_cvt_pk_bf16_f32 %0, %1, %2" : "=v"(a0) : "v"(sa[8*ks+0]), "v"(sa[8*ks+1]));
        asm("v_cvt_pk_bf16_f32 %0, %1, %2" : "=v"(a1) : "v"(sa[8*ks+2]), "v"(sa[8*ks+3]));
        asm("v_cvt_pk_bf16_f32 %0, %1, %2" : "=v"(a2) : "v"(sa[8*ks+4]), "v"(sa[8*ks+5]));
        asm("v_cvt_pk_bf16_f32 %0, %1, %2" : "=v"(a3) : "v"(sa[8*ks+6]), "v"(sa[8*ks+7]));
        asm("v_cvt_pk_bf16_f32 %0, %1, %2" : "=v"(b0) : "v"(sb[8*ks+0]), "v"(sb[8*ks+1]));
        asm("v_cvt_pk_bf16_f32 %0, %1, %2" : "=v"(b1) : "v"(sb[8*ks+2]), "v"(sb[8*ks+3]));
        asm("v_cvt_pk_bf16_f32 %0, %1, %2" : "=v"(b2) : "v"(sb[8*ks+4]), "v"(sb[8*ks+5]));
        asm("v_cvt_pk_bf16_f32 %0, %1, %2" : "=v"(b3) : "v"(sb[8*ks+6]), "v"(sb[8*ks+7]));
        union { unsigned u[4]; bf16x8 v; } pa, pb;
        pa.u[0] = a0; pa.u[1] = a1; pa.u[2] = a2; pa.u[3] = a3;
        pb.u[0] = b0; pb.u[1] = b1; pb.u[2] = b2; pb.u[3] = b3;
        int slice = 2 * ksub + ks;
        __builtin_amdgcn_s_setprio(1);
        #pragma unroll
        for (int dt = 0; dt < 3; ++dt) {
          bf16x8 vf = *(const bf16x8*)(vbl + (slice * 3 + dt) * 1024 + hi * 512 + l31 * 16);
          oa[dt] = __builtin_amdgcn_mfma_f32_32x32x16_bf16(pa.v, vf, oa[dt], 0, 0, 0);
          ob[dt] = __builtin_amdgcn_mfma_f32_32x32x16_bf16(pb.v, vf, ob[dt], 0, 0, 0);
        }
        __builtin_amdgcn_s_setprio(0);
      }
    }
    __syncthreads();     // drains K(t+1)/V(t+1) staging
    cur ^= 1;
  }

  float la = tsa + __shfl_xor(tsa, 32, 64);
  float lb = tsb + __shfl_xor(tsb, 32, 64);

  if constexpr (NKG > 1) {
    // ---- partials: O bf16 (row-layout) + l f32 (col-layout, row = l31) ----
    short* op = Op + (size_t)L * 12288;
    #pragma unroll
    for (int p = 0; p < 4; ++p) {
      #pragma unroll
      for (int jj = 0; jj < 4; ++jj) {
        int qra = w * 64 + 8 * p + 4 * hi + jj;
        op[(size_t)qra * 96 + l31]      = f2bfh(oa[0][4*p+jj]);
        op[(size_t)qra * 96 + 32 + l31] = f2bfh(oa[1][4*p+jj]);
        op[(size_t)qra * 96 + 64 + l31] = f2bfh(oa[2][4*p+jj]);
        int qrb = qra + 32;
        op[(size_t)qrb * 96 + l31]      = f2bfh(ob[0][4*p+jj]);
        op[(size_t)qrb * 96 + 32 + l31] = f2bfh(ob[1][4*p+jj]);
        op[(size_t)qrb * 96 + 64 + l31] = f2bfh(ob[2][4*p+jj]);
      }
    }
    if (hi == 0) {
      lp[(size_t)L * 128 + w * 64 + l31] = la;
      lp[(size_t)L * 128 + w * 64 + 32 + l31] = lb;
    }
  } else {
    __syncthreads();
    float* bcf = (float*)smem;
    if (hi == 0) {
      bcf[w * 64 + l31] = 1.0f / la;
      bcf[w * 64 + 32 + l31] = 1.0f / lb;
    }
    __syncthreads();
    #pragma unroll
    for (int p = 0; p < 4; ++p) {
      #pragma unroll
      for (int jj = 0; jj < 4; ++jj) {
        int qr = 8 * p + 4 * hi + jj;
        float iva = bcf[w * 64 + qr];
        float ivb = bcf[w * 64 + 32 + qr];
        short* xpa = Xb + ((size_t)(n * S_LEN + q0 + w * 64 + qr)) * EMB + h * HDIM + l31;
        xpa[0]  = f2bfh(oa[0][4*p+jj] * iva);
        xpa[32] = f2bfh(oa[1][4*p+jj] * iva);
        xpa[64] = f2bfh(oa[2][4*p+jj] * iva);
        short* xpb = xpa + (size_t)32 * EMB;
        xpb[0]  = f2bfh(ob[0][4*p+jj] * ivb);
        xpb[32] = f2bfh(ob[1][4*p+jj] * ivb);
        xpb[64] = f2bfh(ob[2][4*p+jj] * ivb);
      }
    }
  }
}

// ---------- split-K combine: Xb = (sum_kg O) / (sum_kg l); bf16 partials, 16B ld/st ----------
__global__ __launch_bounds__(256) void combine_kernel(const short* __restrict__ Op,
                                                      const float* __restrict__ lp,
                                                      short* __restrict__ Xb,
                                                      int nkg) {
  int b = blockIdx.x;
  int h = b & 7, j = b >> 3, n = j >> 5, qt = j & 31;
  int q0 = qt * 128;
  int tid = threadIdx.x;
  #pragma unroll 1
  for (int i = 0; i < 6; ++i) {
    int idx = (i * 256 + tid) * 8;
    int qr = idx / 96, d = idx - qr * 96;
    float acc[8] = {0.f, 0.f, 0.f, 0.f, 0.f, 0.f, 0.f, 0.f};
    float l = 0.f;
    for (int kg = 0; kg < nkg; ++kg) {
      size_t blk = (size_t)(kg * 512 + b);
      bf16x8 v = *(const bf16x8*)(Op + blk * 12288 + idx);
      #pragma unroll
      for (int e = 0; e < 8; ++e) acc[e] += bf2f(v[e]);
      l += lp[blk * 128 + qr];
    }
    float iv = 1.0f / l;
    bf16x8 r;
    #pragma unroll
    for (int e = 0; e < 8; ++e) r[e] = f2bfh(acc[e] * iv);
    *(bf16x8*)(Xb + ((size_t)(n * S_LEN + q0 + qr)) * EMB + h * HDIM + d) = r;
  }
}

// ---------- FC: out[m][j] = sum_k X[m][k] * W[j][k] + b[j] ----------
__global__ __launch_bounds__(256) void fc_kernel(const short* __restrict__ Xb,
                                                 const short* __restrict__ Wb,
                                                 const float* __restrict__ bias,
                                                 float* __restrict__ out) {
  int m0 = blockIdx.x * 64, j0 = blockIdx.y * 64;
  int tid = threadIdx.x;
  int w = tid >> 6, lane = tid & 63, lr = lane & 15, lg = lane >> 4;
  f32x4 acc[4];
  #pragma unroll
  for (int jt = 0; jt < 4; ++jt) acc[jt] = (f32x4){0.f, 0.f, 0.f, 0.f};
  const short* xp = Xb + (size_t)(m0 + w * 16 + lr) * EMB + 8 * lg;
  const short* wp = Wb + (size_t)(j0 + lr) * EMB + 8 * lg;
  #pragma unroll 1
  for (int kt = 0; kt < 24; ++kt) {
    bf16x8 a = *(const bf16x8*)(xp + kt * 32);
    #pragma unroll
    for (int jt = 0; jt < 4; ++jt) {
      bf16x8 bw = *(const bf16x8*)(wp + (size_t)(jt * 16) * EMB + kt * 32);
      acc[jt] = __builtin_amdgcn_mfma_f32_16x16x32_bf16(a, bw, acc[jt], 0, 0, 0);
    }
  }
  #pragma unroll
  for (int jt = 0; jt < 4; ++jt) {
    float bb = bias[j0 + jt * 16 + lr];
    #pragma unroll
    for (int i = 0; i < 4; ++i)
      out[(size_t)(m0 + w * 16 + 4 * lg + i) * EMB + j0 + jt * 16 + lr] = acc[jt][i] + bb;
  }
}

extern "C" void kernel_launch(void* const* d_in, const int* in_sizes, int n_in,
                              void* d_out, int out_size, void* d_ws, size_t ws_size,
                              hipStream_t stream) {
  (void)in_sizes; (void)n_in; (void)out_size;
  const float* V = (const float*)d_in[0];
  const float* K = (const float*)d_in[1];
  const float* Q = (const float*)d_in[2];
  const float* W = (const float*)d_in[3];
  const float* B = (const float*)d_in[4];
  float* out = (float*)d_out;
  // ws (shorts): KVT[12582912] | Wb[589824] | Xb[6291456] | Op bf16 | lp f32
  short* KVT = (short*)d_ws;
  short* Wb  = KVT + 12582912;
  short* Xb  = Wb + 589824;
  size_t base_bytes = (size_t)(12582912 + 589824 + 6291456) * 2;
  size_t part_bytes = (size_t)2 * 512 * 12288 * 2 + (size_t)2 * 512 * 128 * 4;
  prep_kernel<<<2336, 256, 0, stream>>>(K, W, V, KVT, Wb);
  if (ws_size >= base_bytes + part_bytes) {
    short* Op = (short*)((char*)d_ws + base_bytes);
    float* lp = (float*)(Op + (size_t)2 * 512 * 12288);
    attn_kernel<2><<<1024, 128, 0, stream>>>(Q, KVT, Xb, Op, lp);
    combine_kernel<<<512, 256, 0, stream>>>(Op, lp, Xb, 2);
  } else {
    attn_kernel<1><<<512, 128, 0, stream>>>(Q, KVT, Xb, nullptr, nullptr);
  }
  fc_kernel<<<dim3(128, 12), 256, 0, stream>>>(Xb, Wb, B, out);
}

// Round 21
// 180.742 us; speedup vs baseline: 1.2600x; 1.1639x over previous
//
#include <hip/hip_runtime.h>
#include <hip/hip_bf16.h>

#define S_LEN 4096
#define EMB 768
#define NHEAD 8
#define HDIM 96

typedef short bf16x8 __attribute__((ext_vector_type(8)));
typedef float f32x4 __attribute__((ext_vector_type(4)));
typedef float f32x16 __attribute__((ext_vector_type(16)));

__device__ __forceinline__ short f2bf(float x) {
  union { float f; unsigned u; } v; v.f = x;
  unsigned r = v.u + 0x7fffu + ((v.u >> 16) & 1u);   // round-to-nearest-even
  return (short)(r >> 16);
}

__device__ __forceinline__ short f2bfh(float x) {
  union { __hip_bfloat16 h; short s; } u;
  u.h = __float2bfloat16(x);
  return u.s;
}

__device__ __forceinline__ float bf2f(short s) {
  union { unsigned u; float f; } v;
  v.u = ((unsigned)(unsigned short)s) << 16;
  return v.f;
}

#define GLOAD_LDS16(gp, lp)                                              \
  __builtin_amdgcn_global_load_lds(                                      \
      (const __attribute__((address_space(1))) unsigned int*)(gp),       \
      (__attribute__((address_space(3))) unsigned int*)(lp), 16, 0, 0)

// ---------- fused prep ----------
// blocks [0,288):      W -> bf16.
// blocks [288,1312):   K half of KVT tile (12KB), BARRIER-FREE: unit u = c*128 +
//                      ksub*64 + hi*32 + l31 holds K[32ksub+l31][16c+8hi..+7] which is
//                      CONTIGUOUS 16B in the source row -> direct gather-convert-store
//                      (no LDS round trip; dst writes stay perfectly coalesced).
// blocks [1312,2336):  V half (12KB): lane-linear sigma layout (sigma = swap key bits
//                      2<->3, matches 32x32 MFMA C/D slots -> P packs identity).
__global__ __launch_bounds__(256) void prep_kernel(const float* __restrict__ K,
                                                   const float* __restrict__ W,
                                                   const float* __restrict__ V,
                                                   short* __restrict__ KVT,
                                                   short* __restrict__ Wb) {
  __shared__ short tlbuf[6656];
  int b = blockIdx.x;
  int tid = threadIdx.x;
  if (b < 288) {
    int t = b * 256 + tid;
    size_t off = (size_t)t * 8;
    float4 a = *(const float4*)(W + off);
    float4 bq = *(const float4*)(W + off + 4);
    bf16x8 r;
    r[0]=f2bf(a.x);  r[1]=f2bf(a.y);  r[2]=f2bf(a.z);  r[3]=f2bf(a.w);
    r[4]=f2bf(bq.x); r[5]=f2bf(bq.y); r[6]=f2bf(bq.z); r[7]=f2bf(bq.w);
    *(bf16x8*)(Wb + off) = r;
    return;
  }
  if (b < 1312) {
    // ---- K tile: direct convert, no LDS, no barriers ----
    int bb = b - 288;
    int n = bb >> 9, h = (bb >> 6) & 7, st = bb & 63;
    int s0 = st * 64;
    const float* kp = K + ((size_t)(n * S_LEN + s0)) * EMB + h * HDIM;
    short* KVp = KVT + ((size_t)((n * NHEAD + h) * 64 + st)) * 12288;
    #pragma unroll
    for (int i = 0; i < 3; ++i) {
      int u = i * 256 + tid;
      int c = u >> 7, rem = u & 127;
      int ksub = (rem >> 6) & 1, hi2 = (rem >> 5) & 1, l31 = rem & 31;
      int key = ksub * 32 + l31;
      const float* src = kp + (size_t)key * EMB + c * 16 + hi2 * 8;
      float4 x0 = ((const float4*)src)[0];
      float4 x1 = ((const float4*)src)[1];
      bf16x8 r;
      r[0]=f2bf(x0.x); r[1]=f2bf(x0.y); r[2]=f2bf(x0.z); r[3]=f2bf(x0.w);
      r[4]=f2bf(x1.x); r[5]=f2bf(x1.y); r[6]=f2bf(x1.z); r[7]=f2bf(x1.w);
      *(bf16x8*)(KVp + (size_t)u * 8) = r;
    }
    return;
  }
  // ---- V tile: lane-linear sigma layout (needs the LDS transpose) ----
  int bb = b - 1312;
  int n = bb >> 9, h = (bb >> 6) & 7, st = bb & 63;
  int s0 = st * 64;
  const float* vp = V + ((size_t)(n * S_LEN + s0)) * EMB + h * HDIM;
  #pragma unroll
  for (int k = 0; k < 6; ++k) {
    int idx = k * 256 + tid;
    int fidx = idx * 4;
    int s = fidx / 96, d = fidx % 96;
    float4 a = *(const float4*)(vp + (size_t)s * EMB + d);
    tlbuf[(d + 0) * 68 + s] = f2bf(a.x);
    tlbuf[(d + 1) * 68 + s] = f2bf(a.y);
    tlbuf[(d + 2) * 68 + s] = f2bf(a.z);
    tlbuf[(d + 3) * 68 + s] = f2bf(a.w);
  }
  __syncthreads();
  short* KVp = KVT + ((size_t)((n * NHEAD + h) * 64 + st)) * 12288 + 6144;
  #pragma unroll
  for (int i = 0; i < 3; ++i) {
    int u = i * 256 + tid;
    int slice = u / 192;
    int rem = u - slice * 192;
    int dt = rem >> 6, hi2 = (rem >> 5) & 1, d5 = rem & 31;
    int d = dt * 32 + d5;
    int kb = 16 * slice + 4 * hi2;
    short4 lo = *(const short4*)&tlbuf[d * 68 + kb];
    short4 hi4 = *(const short4*)&tlbuf[d * 68 + kb + 8];
    bf16x8 r;
    r[0]=lo.x; r[1]=lo.y; r[2]=lo.z; r[3]=lo.w;
    r[4]=hi4.x; r[5]=hi4.y; r[6]=hi4.z; r[7]=hi4.w;
    *(bf16x8*)(KVp + (size_t)u * 8) = r;
  }
}

// ---------- flash attention: byte-identical to r20 (best: ~118us) ----------
template<int NKG>
__global__ __launch_bounds__(128, 2) void attn_kernel(const float* __restrict__ Q,
                                                      const short* __restrict__ KVT,
                                                      short* __restrict__ Xb,
                                                      short* __restrict__ Op,
                                                      float* __restrict__ lp) {
  __shared__ __align__(16) char smem[36864];   // kbuf 12KB @0 | vbuf[2] 12KB @12288
  constexpr int ITERS = S_LEN / NKG / 64;
  int L = blockIdx.x;
  int bb = L & 511;
  int kg = L >> 9;
  int h = bb & 7, j = bb >> 3;
  int n = j >> 5, qt = j & 31;
  int q0 = qt * 128;
  int tid = threadIdx.x;
  int w = tid >> 6, lane = tid & 63, l31 = lane & 31, hi = lane >> 5;

  const float kAdj = 0.14724512f;  // (1/sqrt(96)) * log2(e), folded into Q
  bf16x8 qfa[6], qfb[6];
  #pragma unroll
  for (int sub = 0; sub < 2; ++sub) {
    const float* qp = Q + ((size_t)(n * S_LEN + q0 + w * 64 + sub * 32 + l31)) * EMB
                        + h * HDIM + 8 * hi;
    #pragma unroll
    for (int c = 0; c < 6; ++c) {
      float4 a = *(const float4*)(qp + 16 * c);
      float4 bq = *(const float4*)(qp + 16 * c + 4);
      bf16x8 r;
      r[0]=f2bf(a.x*kAdj);  r[1]=f2bf(a.y*kAdj);  r[2]=f2bf(a.z*kAdj);  r[3]=f2bf(a.w*kAdj);
      r[4]=f2bf(bq.x*kAdj); r[5]=f2bf(bq.y*kAdj); r[6]=f2bf(bq.z*kAdj); r[7]=f2bf(bq.w*kAdj);
      if (sub == 0) qfa[c] = r; else qfb[c] = r;
    }
  }

  const short* gKV = KVT + ((size_t)((n * NHEAD + h) * 64 + kg * ITERS)) * 12288
                        + (size_t)(w * 6) * 512 + lane * 8;
  char* kbuf = smem;
  char* vbuf = smem + 12288;
  char* kdst = kbuf + w * 6144;
  char* vdst0 = vbuf + w * 6144;

  #pragma unroll
  for (int i = 0; i < 6; ++i) {
    GLOAD_LDS16(gKV + i * 512, kdst + i * 1024);
    GLOAD_LDS16(gKV + 6144 + i * 512, vdst0 + i * 1024);
  }
  __syncthreads();

  f32x16 oa[3], ob[3];
  #pragma unroll
  for (int dt = 0; dt < 3; ++dt) { oa[dt] = (f32x16){}; ob[dt] = (f32x16){}; }
  float tsa = 0.f, tsb = 0.f;

  int cur = 0;
  #pragma unroll 1
  for (int t = 0; t < ITERS; ++t) {
    if (t < ITERS - 1) {
      const short* src = gKV + (size_t)(t + 1) * 12288;
      char* vd = vbuf + (cur ^ 1) * 12288 + w * 6144;
      #pragma unroll
      for (int i = 0; i < 6; ++i)
        GLOAD_LDS16(src + 6144 + i * 512, vd + i * 1024);
    }

    f32x16 s0a = (f32x16){}, s1a = (f32x16){}, s0b = (f32x16){}, s1b = (f32x16){};
    __builtin_amdgcn_s_setprio(1);
    #pragma unroll
    for (int c = 0; c < 6; ++c) {
      bf16x8 kf0 = *(const bf16x8*)(kbuf + c * 2048 + lane * 16);
      bf16x8 kf1 = *(const bf16x8*)(kbuf + c * 2048 + 1024 + lane * 16);
      s0a = __builtin_amdgcn_mfma_f32_32x32x16_bf16(kf0, qfa[c], s0a, 0, 0, 0);
      s0b = __builtin_amdgcn_mfma_f32_32x32x16_bf16(kf0, qfb[c], s0b, 0, 0, 0);
      s1a = __builtin_amdgcn_mfma_f32_32x32x16_bf16(kf1, qfa[c], s1a, 0, 0, 0);
      s1b = __builtin_amdgcn_mfma_f32_32x32x16_bf16(kf1, qfb[c], s1b, 0, 0, 0);
    }
    __builtin_amdgcn_s_setprio(0);
    __syncthreads();

    if (t < ITERS - 1) {
      const short* src = gKV + (size_t)(t + 1) * 12288;
      #pragma unroll
      for (int i = 0; i < 6; ++i)
        GLOAD_LDS16(src + i * 512, kdst + i * 1024);
    }

    #pragma unroll
    for (int r = 0; r < 16; ++r) s0a[r] = __builtin_amdgcn_exp2f(s0a[r]);
    #pragma unroll
    for (int r = 0; r < 16; ++r) s1a[r] = __builtin_amdgcn_exp2f(s1a[r]);
    #pragma unroll
    for (int r = 0; r < 16; ++r) s0b[r] = __builtin_amdgcn_exp2f(s0b[r]);
    #pragma unroll
    for (int r = 0; r < 16; ++r) s1b[r] = __builtin_amdgcn_exp2f(s1b[r]);
    {
      float a0 = (s0a[0]+s0a[1])+(s0a[2]+s0a[3]), a1 = (s0a[4]+s0a[5])+(s0a[6]+s0a[7]);
      float a2 = (s0a[8]+s0a[9])+(s0a[10]+s0a[11]), a3 = (s0a[12]+s0a[13])+(s0a[14]+s0a[15]);
      float b0 = (s1a[0]+s1a[1])+(s1a[2]+s1a[3]), b1 = (s1a[4]+s1a[5])+(s1a[6]+s1a[7]);
      float b2 = (s1a[8]+s1a[9])+(s1a[10]+s1a[11]), b3 = (s1a[12]+s1a[13])+(s1a[14]+s1a[15]);
      tsa += ((a0+a1)+(a2+a3)) + ((b0+b1)+(b2+b3));
      float c0 = (s0b[0]+s0b[1])+(s0b[2]+s0b[3]), c1 = (s0b[4]+s0b[5])+(s0b[6]+s0b[7]);
      float c2 = (s0b[8]+s0b[9])+(s0b[10]+s0b[11]), c3 = (s0b[12]+s0b[13])+(s0b[14]+s0b[15]);
      float d0_ = (s1b[0]+s1b[1])+(s1b[2]+s1b[3]), d1_ = (s1b[4]+s1b[5])+(s1b[6]+s1b[7]);
      float d2_ = (s1b[8]+s1b[9])+(s1b[10]+s1b[11]), d3_ = (s1b[12]+s1b[13])+(s1b[14]+s1b[15]);
      tsb += ((c0+c1)+(c2+c3)) + ((d0_+d1_)+(d2_+d3_));
    }

    const char* vbl = vbuf + cur * 12288;
    #pragma unroll
    for (int ksub = 0; ksub < 2; ++ksub) {
      const f32x16& sa = ksub ? s1a : s0a;
      const f32x16& sb = ksub ? s1b : s0b;
      #pragma unroll
      for (int ks = 0; ks < 2; ++ks) {
        unsigned a0, a1, a2, a3, b0, b1, b2, b3;
        asm("v_cvt_pk_bf16_f32 %0, %1, %2" : "=v"(a0) : "v"(sa[8*ks+0]), "v"(sa[8*ks+1]));
        asm("v_cvt_pk_bf16_f32 %0, %1, %2" : "=v"(a1) : "v"(sa[8*ks+2]), "v"(sa[8*ks+3]));
        asm("v_cvt_pk_bf16_f32 %0, %1, %2" : "=v"(a2) : "v"(sa[8*ks+4]), "v"(sa[8*ks+5]));
        asm("v_cvt_pk_bf16_f32 %0, %1, %2" : "=v"(a3) : "v"(sa[8*ks+6]), "v"(sa[8*ks+7]));
        asm("v_cvt_pk_bf16_f32 %0, %1, %2" : "=v"(b0) : "v"(sb[8*ks+0]), "v"(sb[8*ks+1]));
        asm("v_cvt_pk_bf16_f32 %0, %1, %2" : "=v"(b1) : "v"(sb[8*ks+2]), "v"(sb[8*ks+3]));
        asm("v_cvt_pk_bf16_f32 %0, %1, %2" : "=v"(b2) : "v"(sb[8*ks+4]), "v"(sb[8*ks+5]));
        asm("v_cvt_pk_bf16_f32 %0, %1, %2" : "=v"(b3) : "v"(sb[8*ks+6]), "v"(sb[8*ks+7]));
        union { unsigned u[4]; bf16x8 v; } pa, pb;
        pa.u[0] = a0; pa.u[1] = a1; pa.u[2] = a2; pa.u[3] = a3;
        pb.u[0] = b0; pb.u[1] = b1; pb.u[2] = b2; pb.u[3] = b3;
        int slice = 2 * ksub + ks;
        __builtin_amdgcn_s_setprio(1);
        #pragma unroll
        for (int dt = 0; dt < 3; ++dt) {
          bf16x8 vf = *(const bf16x8*)(vbl + (slice * 3 + dt) * 1024 + hi * 512 + l31 * 16);
          oa[dt] = __builtin_amdgcn_mfma_f32_32x32x16_bf16(pa.v, vf, oa[dt], 0, 0, 0);
          ob[dt] = __builtin_amdgcn_mfma_f32_32x32x16_bf16(pb.v, vf, ob[dt], 0, 0, 0);
        }
        __builtin_amdgcn_s_setprio(0);
      }
    }
    __syncthreads();
    cur ^= 1;
  }

  float la = tsa + __shfl_xor(tsa, 32, 64);
  float lb = tsb + __shfl_xor(tsb, 32, 64);

  if constexpr (NKG > 1) {
    short* op = Op + (size_t)L * 12288;
    #pragma unroll
    for (int p = 0; p < 4; ++p) {
      #pragma unroll
      for (int jj = 0; jj < 4; ++jj) {
        int qra = w * 64 + 8 * p + 4 * hi + jj;
        op[(size_t)qra * 96 + l31]      = f2bfh(oa[0][4*p+jj]);
        op[(size_t)qra * 96 + 32 + l31] = f2bfh(oa[1][4*p+jj]);
        op[(size_t)qra * 96 + 64 + l31] = f2bfh(oa[2][4*p+jj]);
        int qrb = qra + 32;
        op[(size_t)qrb * 96 + l31]      = f2bfh(ob[0][4*p+jj]);
        op[(size_t)qrb * 96 + 32 + l31] = f2bfh(ob[1][4*p+jj]);
        op[(size_t)qrb * 96 + 64 + l31] = f2bfh(ob[2][4*p+jj]);
      }
    }
    if (hi == 0) {
      lp[(size_t)L * 128 + w * 64 + l31] = la;
      lp[(size_t)L * 128 + w * 64 + 32 + l31] = lb;
    }
  } else {
    __syncthreads();
    float* bcf = (float*)smem;
    if (hi == 0) {
      bcf[w * 64 + l31] = 1.0f / la;
      bcf[w * 64 + 32 + l31] = 1.0f / lb;
    }
    __syncthreads();
    #pragma unroll
    for (int p = 0; p < 4; ++p) {
      #pragma unroll
      for (int jj = 0; jj < 4; ++jj) {
        int qr = 8 * p + 4 * hi + jj;
        float iva = bcf[w * 64 + qr];
        float ivb = bcf[w * 64 + 32 + qr];
        short* xpa = Xb + ((size_t)(n * S_LEN + q0 + w * 64 + qr)) * EMB + h * HDIM + l31;
        xpa[0]  = f2bfh(oa[0][4*p+jj] * iva);
        xpa[32] = f2bfh(oa[1][4*p+jj] * iva);
        xpa[64] = f2bfh(oa[2][4*p+jj] * iva);
        short* xpb = xpa + (size_t)32 * EMB;
        xpb[0]  = f2bfh(ob[0][4*p+jj] * ivb);
        xpb[32] = f2bfh(ob[1][4*p+jj] * ivb);
        xpb[64] = f2bfh(ob[2][4*p+jj] * ivb);
      }
    }
  }
}

// ---------- split-K combine (unchanged from r20) ----------
__global__ __launch_bounds__(256) void combine_kernel(const short* __restrict__ Op,
                                                      const float* __restrict__ lp,
                                                      short* __restrict__ Xb,
                                                      int nkg) {
  int b = blockIdx.x;
  int h = b & 7, j = b >> 3, n = j >> 5, qt = j & 31;
  int q0 = qt * 128;
  int tid = threadIdx.x;
  #pragma unroll 1
  for (int i = 0; i < 6; ++i) {
    int idx = (i * 256 + tid) * 8;
    int qr = idx / 96, d = idx - qr * 96;
    float acc[8] = {0.f, 0.f, 0.f, 0.f, 0.f, 0.f, 0.f, 0.f};
    float l = 0.f;
    for (int kg = 0; kg < nkg; ++kg) {
      size_t blk = (size_t)(kg * 512 + b);
      bf16x8 v = *(const bf16x8*)(Op + blk * 12288 + idx);
      #pragma unroll
      for (int e = 0; e < 8; ++e) acc[e] += bf2f(v[e]);
      l += lp[blk * 128 + qr];
    }
    float iv = 1.0f / l;
    bf16x8 r;
    #pragma unroll
    for (int e = 0; e < 8; ++e) r[e] = f2bfh(acc[e] * iv);
    *(bf16x8*)(Xb + ((size_t)(n * S_LEN + q0 + qr)) * EMB + h * HDIM + d) = r;
  }
}

// ---------- FC: 128-row m-tiles; each wave = two 16-row A-subtiles sharing W frags ----------
// grid (64,12): block covers m-rows [m0, m0+128), j-cols [j0, j0+64). Wave w handles
// m-rows m0 + w*32 .. +31. Per kt: 2 A-loads + 4 W-loads feed 8 MFMA (2x the MFMA per
// W-load vs r20). #pragma unroll 2 lets the compiler pipeline next-kt loads under MFMA.
__global__ __launch_bounds__(256) void fc_kernel(const short* __restrict__ Xb,
                                                 const short* __restrict__ Wb,
                                                 const float* __restrict__ bias,
                                                 float* __restrict__ out) {
  int m0 = blockIdx.x * 128, j0 = blockIdx.y * 64;
  int tid = threadIdx.x;
  int w = tid >> 6, lane = tid & 63, lr = lane & 15, lg = lane >> 4;
  f32x4 acc[2][4];
  #pragma unroll
  for (int sub = 0; sub < 2; ++sub)
    #pragma unroll
    for (int jt = 0; jt < 4; ++jt) acc[sub][jt] = (f32x4){0.f, 0.f, 0.f, 0.f};
  const short* xp0 = Xb + (size_t)(m0 + w * 32 + lr) * EMB + 8 * lg;
  const short* xp1 = xp0 + (size_t)16 * EMB;
  const short* wp = Wb + (size_t)(j0 + lr) * EMB + 8 * lg;
  #pragma unroll 2
  for (int kt = 0; kt < 24; ++kt) {
    bf16x8 a0 = *(const bf16x8*)(xp0 + kt * 32);
    bf16x8 a1 = *(const bf16x8*)(xp1 + kt * 32);
    #pragma unroll
    for (int jt = 0; jt < 4; ++jt) {
      bf16x8 bw = *(const bf16x8*)(wp + (size_t)(jt * 16) * EMB + kt * 32);
      acc[0][jt] = __builtin_amdgcn_mfma_f32_16x16x32_bf16(a0, bw, acc[0][jt], 0, 0, 0);
      acc[1][jt] = __builtin_amdgcn_mfma_f32_16x16x32_bf16(a1, bw, acc[1][jt], 0, 0, 0);
    }
  }
  #pragma unroll
  for (int jt = 0; jt < 4; ++jt) {
    float bb = bias[j0 + jt * 16 + lr];
    #pragma unroll
    for (int sub = 0; sub < 2; ++sub) {
      #pragma unroll
      for (int i = 0; i < 4; ++i)
        out[(size_t)(m0 + w * 32 + sub * 16 + 4 * lg + i) * EMB + j0 + jt * 16 + lr]
            = acc[sub][jt][i] + bb;
    }
  }
}

extern "C" void kernel_launch(void* const* d_in, const int* in_sizes, int n_in,
                              void* d_out, int out_size, void* d_ws, size_t ws_size,
                              hipStream_t stream) {
  (void)in_sizes; (void)n_in; (void)out_size;
  const float* V = (const float*)d_in[0];
  const float* K = (const float*)d_in[1];
  const float* Q = (const float*)d_in[2];
  const float* W = (const float*)d_in[3];
  const float* B = (const float*)d_in[4];
  float* out = (float*)d_out;
  // ws (shorts): KVT[12582912] | Wb[589824] | Xb[6291456] | Op bf16 | lp f32
  short* KVT = (short*)d_ws;
  short* Wb  = KVT + 12582912;
  short* Xb  = Wb + 589824;
  size_t base_bytes = (size_t)(12582912 + 589824 + 6291456) * 2;
  size_t part_bytes = (size_t)2 * 512 * 12288 * 2 + (size_t)2 * 512 * 128 * 4;
  prep_kernel<<<2336, 256, 0, stream>>>(K, W, V, KVT, Wb);
  if (ws_size >= base_bytes + part_bytes) {
    short* Op = (short*)((char*)d_ws + base_bytes);
    float* lp = (float*)(Op + (size_t)2 * 512 * 12288);
    attn_kernel<2><<<1024, 128, 0, stream>>>(Q, KVT, Xb, Op, lp);
    combine_kernel<<<512, 256, 0, stream>>>(Op, lp, Xb, 2);
  } else {
    attn_kernel<1><<<512, 128, 0, stream>>>(Q, KVT, Xb, nullptr, nullptr);
  }
  fc_kernel<<<dim3(64, 12), 256, 0, stream>>>(Xb, Wb, B, out);
}

// Round 22
// 175.295 us; speedup vs baseline: 1.2992x; 1.0311x over previous
//
#include <hip/hip_runtime.h>
#include <hip/hip_bf16.h>

#define S_LEN 4096
#define EMB 768
#define NHEAD 8
#define HDIM 96

typedef short bf16x8 __attribute__((ext_vector_type(8)));
typedef float f32x4 __attribute__((ext_vector_type(4)));
typedef float f32x16 __attribute__((ext_vector_type(16)));

__device__ __forceinline__ short f2bf(float x) {
  union { float f; unsigned u; } v; v.f = x;
  unsigned r = v.u + 0x7fffu + ((v.u >> 16) & 1u);   // round-to-nearest-even
  return (short)(r >> 16);
}

__device__ __forceinline__ short f2bfh(float x) {
  union { __hip_bfloat16 h; short s; } u;
  u.h = __float2bfloat16(x);
  return u.s;
}

__device__ __forceinline__ float bf2f(short s) {
  union { unsigned u; float f; } v;
  v.u = ((unsigned)(unsigned short)s) << 16;
  return v.f;
}

#define GLOAD_LDS16(gp, lp)                                              \
  __builtin_amdgcn_global_load_lds(                                      \
      (const __attribute__((address_space(1))) unsigned int*)(gp),       \
      (__attribute__((address_space(3))) unsigned int*)(lp), 16, 0, 0)

// ---------- fused prep (byte-identical to r21) ----------
__global__ __launch_bounds__(256) void prep_kernel(const float* __restrict__ K,
                                                   const float* __restrict__ W,
                                                   const float* __restrict__ V,
                                                   short* __restrict__ KVT,
                                                   short* __restrict__ Wb) {
  __shared__ short tlbuf[6656];
  int b = blockIdx.x;
  int tid = threadIdx.x;
  if (b < 288) {
    int t = b * 256 + tid;
    size_t off = (size_t)t * 8;
    float4 a = *(const float4*)(W + off);
    float4 bq = *(const float4*)(W + off + 4);
    bf16x8 r;
    r[0]=f2bf(a.x);  r[1]=f2bf(a.y);  r[2]=f2bf(a.z);  r[3]=f2bf(a.w);
    r[4]=f2bf(bq.x); r[5]=f2bf(bq.y); r[6]=f2bf(bq.z); r[7]=f2bf(bq.w);
    *(bf16x8*)(Wb + off) = r;
    return;
  }
  if (b < 1312) {
    // K tile: direct convert, no LDS, no barriers (source 16B contiguous)
    int bb = b - 288;
    int n = bb >> 9, h = (bb >> 6) & 7, st = bb & 63;
    int s0 = st * 64;
    const float* kp = K + ((size_t)(n * S_LEN + s0)) * EMB + h * HDIM;
    short* KVp = KVT + ((size_t)((n * NHEAD + h) * 64 + st)) * 12288;
    #pragma unroll
    for (int i = 0; i < 3; ++i) {
      int u = i * 256 + tid;
      int c = u >> 7, rem = u & 127;
      int ksub = (rem >> 6) & 1, hi2 = (rem >> 5) & 1, l31 = rem & 31;
      int key = ksub * 32 + l31;
      const float* src = kp + (size_t)key * EMB + c * 16 + hi2 * 8;
      float4 x0 = ((const float4*)src)[0];
      float4 x1 = ((const float4*)src)[1];
      bf16x8 r;
      r[0]=f2bf(x0.x); r[1]=f2bf(x0.y); r[2]=f2bf(x0.z); r[3]=f2bf(x0.w);
      r[4]=f2bf(x1.x); r[5]=f2bf(x1.y); r[6]=f2bf(x1.z); r[7]=f2bf(x1.w);
      *(bf16x8*)(KVp + (size_t)u * 8) = r;
    }
    return;
  }
  // V tile: lane-linear sigma layout (sigma = swap key bits 2<->3)
  int bb = b - 1312;
  int n = bb >> 9, h = (bb >> 6) & 7, st = bb & 63;
  int s0 = st * 64;
  const float* vp = V + ((size_t)(n * S_LEN + s0)) * EMB + h * HDIM;
  #pragma unroll
  for (int k = 0; k < 6; ++k) {
    int idx = k * 256 + tid;
    int fidx = idx * 4;
    int s = fidx / 96, d = fidx % 96;
    float4 a = *(const float4*)(vp + (size_t)s * EMB + d);
    tlbuf[(d + 0) * 68 + s] = f2bf(a.x);
    tlbuf[(d + 1) * 68 + s] = f2bf(a.y);
    tlbuf[(d + 2) * 68 + s] = f2bf(a.z);
    tlbuf[(d + 3) * 68 + s] = f2bf(a.w);
  }
  __syncthreads();
  short* KVp = KVT + ((size_t)((n * NHEAD + h) * 64 + st)) * 12288 + 6144;
  #pragma unroll
  for (int i = 0; i < 3; ++i) {
    int u = i * 256 + tid;
    int slice = u / 192;
    int rem = u - slice * 192;
    int dt = rem >> 6, hi2 = (rem >> 5) & 1, d5 = rem & 31;
    int d = dt * 32 + d5;
    int kb = 16 * slice + 4 * hi2;
    short4 lo = *(const short4*)&tlbuf[d * 68 + kb];
    short4 hi4 = *(const short4*)&tlbuf[d * 68 + kb + 8];
    bf16x8 r;
    r[0]=lo.x; r[1]=lo.y; r[2]=lo.z; r[3]=lo.w;
    r[4]=hi4.x; r[5]=hi4.y; r[6]=hi4.z; r[7]=hi4.w;
    *(bf16x8*)(KVp + (size_t)u * 8) = r;
  }
}

// ---------- flash attention: byte-identical to r20/r21 (best known, ~117us) ----------
template<int NKG>
__global__ __launch_bounds__(128, 2) void attn_kernel(const float* __restrict__ Q,
                                                      const short* __restrict__ KVT,
                                                      short* __restrict__ Xb,
                                                      short* __restrict__ Op,
                                                      float* __restrict__ lp) {
  __shared__ __align__(16) char smem[36864];   // kbuf 12KB @0 | vbuf[2] 12KB @12288
  constexpr int ITERS = S_LEN / NKG / 64;
  int L = blockIdx.x;
  int bb = L & 511;
  int kg = L >> 9;
  int h = bb & 7, j = bb >> 3;
  int n = j >> 5, qt = j & 31;
  int q0 = qt * 128;
  int tid = threadIdx.x;
  int w = tid >> 6, lane = tid & 63, l31 = lane & 31, hi = lane >> 5;

  const float kAdj = 0.14724512f;  // (1/sqrt(96)) * log2(e), folded into Q
  bf16x8 qfa[6], qfb[6];
  #pragma unroll
  for (int sub = 0; sub < 2; ++sub) {
    const float* qp = Q + ((size_t)(n * S_LEN + q0 + w * 64 + sub * 32 + l31)) * EMB
                        + h * HDIM + 8 * hi;
    #pragma unroll
    for (int c = 0; c < 6; ++c) {
      float4 a = *(const float4*)(qp + 16 * c);
      float4 bq = *(const float4*)(qp + 16 * c + 4);
      bf16x8 r;
      r[0]=f2bf(a.x*kAdj);  r[1]=f2bf(a.y*kAdj);  r[2]=f2bf(a.z*kAdj);  r[3]=f2bf(a.w*kAdj);
      r[4]=f2bf(bq.x*kAdj); r[5]=f2bf(bq.y*kAdj); r[6]=f2bf(bq.z*kAdj); r[7]=f2bf(bq.w*kAdj);
      if (sub == 0) qfa[c] = r; else qfb[c] = r;
    }
  }

  const short* gKV = KVT + ((size_t)((n * NHEAD + h) * 64 + kg * ITERS)) * 12288
                        + (size_t)(w * 6) * 512 + lane * 8;
  char* kbuf = smem;
  char* vbuf = smem + 12288;
  char* kdst = kbuf + w * 6144;
  char* vdst0 = vbuf + w * 6144;

  #pragma unroll
  for (int i = 0; i < 6; ++i) {
    GLOAD_LDS16(gKV + i * 512, kdst + i * 1024);
    GLOAD_LDS16(gKV + 6144 + i * 512, vdst0 + i * 1024);
  }
  __syncthreads();

  f32x16 oa[3], ob[3];
  #pragma unroll
  for (int dt = 0; dt < 3; ++dt) { oa[dt] = (f32x16){}; ob[dt] = (f32x16){}; }
  float tsa = 0.f, tsb = 0.f;

  int cur = 0;
  #pragma unroll 1
  for (int t = 0; t < ITERS; ++t) {
    if (t < ITERS - 1) {
      const short* src = gKV + (size_t)(t + 1) * 12288;
      char* vd = vbuf + (cur ^ 1) * 12288 + w * 6144;
      #pragma unroll
      for (int i = 0; i < 6; ++i)
        GLOAD_LDS16(src + 6144 + i * 512, vd + i * 1024);
    }

    f32x16 s0a = (f32x16){}, s1a = (f32x16){}, s0b = (f32x16){}, s1b = (f32x16){};
    __builtin_amdgcn_s_setprio(1);
    #pragma unroll
    for (int c = 0; c < 6; ++c) {
      bf16x8 kf0 = *(const bf16x8*)(kbuf + c * 2048 + lane * 16);
      bf16x8 kf1 = *(const bf16x8*)(kbuf + c * 2048 + 1024 + lane * 16);
      s0a = __builtin_amdgcn_mfma_f32_32x32x16_bf16(kf0, qfa[c], s0a, 0, 0, 0);
      s0b = __builtin_amdgcn_mfma_f32_32x32x16_bf16(kf0, qfb[c], s0b, 0, 0, 0);
      s1a = __builtin_amdgcn_mfma_f32_32x32x16_bf16(kf1, qfa[c], s1a, 0, 0, 0);
      s1b = __builtin_amdgcn_mfma_f32_32x32x16_bf16(kf1, qfb[c], s1b, 0, 0, 0);
    }
    __builtin_amdgcn_s_setprio(0);
    __syncthreads();

    if (t < ITERS - 1) {
      const short* src = gKV + (size_t)(t + 1) * 12288;
      #pragma unroll
      for (int i = 0; i < 6; ++i)
        GLOAD_LDS16(src + i * 512, kdst + i * 1024);
    }

    #pragma unroll
    for (int r = 0; r < 16; ++r) s0a[r] = __builtin_amdgcn_exp2f(s0a[r]);
    #pragma unroll
    for (int r = 0; r < 16; ++r) s1a[r] = __builtin_amdgcn_exp2f(s1a[r]);
    #pragma unroll
    for (int r = 0; r < 16; ++r) s0b[r] = __builtin_amdgcn_exp2f(s0b[r]);
    #pragma unroll
    for (int r = 0; r < 16; ++r) s1b[r] = __builtin_amdgcn_exp2f(s1b[r]);
    {
      float a0 = (s0a[0]+s0a[1])+(s0a[2]+s0a[3]), a1 = (s0a[4]+s0a[5])+(s0a[6]+s0a[7]);
      float a2 = (s0a[8]+s0a[9])+(s0a[10]+s0a[11]), a3 = (s0a[12]+s0a[13])+(s0a[14]+s0a[15]);
      float b0 = (s1a[0]+s1a[1])+(s1a[2]+s1a[3]), b1 = (s1a[4]+s1a[5])+(s1a[6]+s1a[7]);
      float b2 = (s1a[8]+s1a[9])+(s1a[10]+s1a[11]), b3 = (s1a[12]+s1a[13])+(s1a[14]+s1a[15]);
      tsa += ((a0+a1)+(a2+a3)) + ((b0+b1)+(b2+b3));
      float c0 = (s0b[0]+s0b[1])+(s0b[2]+s0b[3]), c1 = (s0b[4]+s0b[5])+(s0b[6]+s0b[7]);
      float c2 = (s0b[8]+s0b[9])+(s0b[10]+s0b[11]), c3 = (s0b[12]+s0b[13])+(s0b[14]+s0b[15]);
      float d0_ = (s1b[0]+s1b[1])+(s1b[2]+s1b[3]), d1_ = (s1b[4]+s1b[5])+(s1b[6]+s1b[7]);
      float d2_ = (s1b[8]+s1b[9])+(s1b[10]+s1b[11]), d3_ = (s1b[12]+s1b[13])+(s1b[14]+s1b[15]);
      tsb += ((c0+c1)+(c2+c3)) + ((d0_+d1_)+(d2_+d3_));
    }

    const char* vbl = vbuf + cur * 12288;
    #pragma unroll
    for (int ksub = 0; ksub < 2; ++ksub) {
      const f32x16& sa = ksub ? s1a : s0a;
      const f32x16& sb = ksub ? s1b : s0b;
      #pragma unroll
      for (int ks = 0; ks < 2; ++ks) {
        unsigned a0, a1, a2, a3, b0, b1, b2, b3;
        asm("v_cvt_pk_bf16_f32 %0, %1, %2" : "=v"(a0) : "v"(sa[8*ks+0]), "v"(sa[8*ks+1]));
        asm("v_cvt_pk_bf16_f32 %0, %1, %2" : "=v"(a1) : "v"(sa[8*ks+2]), "v"(sa[8*ks+3]));
        asm("v_cvt_pk_bf16_f32 %0, %1, %2" : "=v"(a2) : "v"(sa[8*ks+4]), "v"(sa[8*ks+5]));
        asm("v_cvt_pk_bf16_f32 %0, %1, %2" : "=v"(a3) : "v"(sa[8*ks+6]), "v"(sa[8*ks+7]));
        asm("v_cvt_pk_bf16_f32 %0, %1, %2" : "=v"(b0) : "v"(sb[8*ks+0]), "v"(sb[8*ks+1]));
        asm("v_cvt_pk_bf16_f32 %0, %1, %2" : "=v"(b1) : "v"(sb[8*ks+2]), "v"(sb[8*ks+3]));
        asm("v_cvt_pk_bf16_f32 %0, %1, %2" : "=v"(b2) : "v"(sb[8*ks+4]), "v"(sb[8*ks+5]));
        asm("v_cvt_pk_bf16_f32 %0, %1, %2" : "=v"(b3) : "v"(sb[8*ks+6]), "v"(sb[8*ks+7]));
        union { unsigned u[4]; bf16x8 v; } pa, pb;
        pa.u[0] = a0; pa.u[1] = a1; pa.u[2] = a2; pa.u[3] = a3;
        pb.u[0] = b0; pb.u[1] = b1; pb.u[2] = b2; pb.u[3] = b3;
        int slice = 2 * ksub + ks;
        __builtin_amdgcn_s_setprio(1);
        #pragma unroll
        for (int dt = 0; dt < 3; ++dt) {
          bf16x8 vf = *(const bf16x8*)(vbl + (slice * 3 + dt) * 1024 + hi * 512 + l31 * 16);
          oa[dt] = __builtin_amdgcn_mfma_f32_32x32x16_bf16(pa.v, vf, oa[dt], 0, 0, 0);
          ob[dt] = __builtin_amdgcn_mfma_f32_32x32x16_bf16(pb.v, vf, ob[dt], 0, 0, 0);
        }
        __builtin_amdgcn_s_setprio(0);
      }
    }
    __syncthreads();
    cur ^= 1;
  }

  float la = tsa + __shfl_xor(tsa, 32, 64);
  float lb = tsb + __shfl_xor(tsb, 32, 64);

  if constexpr (NKG > 1) {
    short* op = Op + (size_t)L * 12288;
    #pragma unroll
    for (int p = 0; p < 4; ++p) {
      #pragma unroll
      for (int jj = 0; jj < 4; ++jj) {
        int qra = w * 64 + 8 * p + 4 * hi + jj;
        op[(size_t)qra * 96 + l31]      = f2bfh(oa[0][4*p+jj]);
        op[(size_t)qra * 96 + 32 + l31] = f2bfh(oa[1][4*p+jj]);
        op[(size_t)qra * 96 + 64 + l31] = f2bfh(oa[2][4*p+jj]);
        int qrb = qra + 32;
        op[(size_t)qrb * 96 + l31]      = f2bfh(ob[0][4*p+jj]);
        op[(size_t)qrb * 96 + 32 + l31] = f2bfh(ob[1][4*p+jj]);
        op[(size_t)qrb * 96 + 64 + l31] = f2bfh(ob[2][4*p+jj]);
      }
    }
    if (hi == 0) {
      lp[(size_t)L * 128 + w * 64 + l31] = la;
      lp[(size_t)L * 128 + w * 64 + 32 + l31] = lb;
    }
  } else {
    __syncthreads();
    float* bcf = (float*)smem;
    if (hi == 0) {
      bcf[w * 64 + l31] = 1.0f / la;
      bcf[w * 64 + 32 + l31] = 1.0f / lb;
    }
    __syncthreads();
    #pragma unroll
    for (int p = 0; p < 4; ++p) {
      #pragma unroll
      for (int jj = 0; jj < 4; ++jj) {
        int qr = 8 * p + 4 * hi + jj;
        float iva = bcf[w * 64 + qr];
        float ivb = bcf[w * 64 + 32 + qr];
        short* xpa = Xb + ((size_t)(n * S_LEN + q0 + w * 64 + qr)) * EMB + h * HDIM + l31;
        xpa[0]  = f2bfh(oa[0][4*p+jj] * iva);
        xpa[32] = f2bfh(oa[1][4*p+jj] * iva);
        xpa[64] = f2bfh(oa[2][4*p+jj] * iva);
        short* xpb = xpa + (size_t)32 * EMB;
        xpb[0]  = f2bfh(ob[0][4*p+jj] * ivb);
        xpb[32] = f2bfh(ob[1][4*p+jj] * ivb);
        xpb[64] = f2bfh(ob[2][4*p+jj] * ivb);
      }
    }
  }
}

// ---------- fused FC: combine split-K partials inline, then GEMM + bias ----------
// Block covers m-rows [m0, m0+128) x j-cols [j0, j0+64). All 128 rows share (n, qt)
// since m0 is a multiple of 128. A-fragment built on the fly:
//   A[r][k] = (bf2f(Op[L0(h)][qrow*96+d]) + bf2f(Op[L1(h)][qrow*96+d])) * invl[r][h]
// where h = k/96, d = k%96 (aligned 8-runs never cross heads: 96 % 8 == 0).
// invl precomputed in regs (2 rows x 8 heads). VALU combine work overlaps the MFMA pipe.
__global__ __launch_bounds__(256) void fc_fused_kernel(const short* __restrict__ Op,
                                                       const float* __restrict__ lp,
                                                       const short* __restrict__ Wb,
                                                       const float* __restrict__ bias,
                                                       float* __restrict__ out) {
  int m0 = blockIdx.x * 128, j0 = blockIdx.y * 64;
  int tid = threadIdx.x;
  int w = tid >> 6, lane = tid & 63, lr = lane & 15, lg = lane >> 4;
  int n = m0 >> 12, qt = (m0 & 4095) >> 7;
  int bbase = (n * 32 + qt) * 8;                 // block index of head 0 (kg=0)
  int qrow0 = w * 32 + lr, qrow1 = qrow0 + 16;

  // per-(row, head) inverse l
  float il0[8], il1[8];
  #pragma unroll
  for (int h = 0; h < 8; ++h) {
    size_t L0 = (size_t)(bbase + h), L1 = L0 + 512;
    il0[h] = 1.0f / (lp[L0 * 128 + qrow0] + lp[L1 * 128 + qrow0]);
    il1[h] = 1.0f / (lp[L0 * 128 + qrow1] + lp[L1 * 128 + qrow1]);
  }

  f32x4 acc[2][4];
  #pragma unroll
  for (int sub = 0; sub < 2; ++sub)
    #pragma unroll
    for (int jt = 0; jt < 4; ++jt) acc[sub][jt] = (f32x4){0.f, 0.f, 0.f, 0.f};

  const short* wp = Wb + (size_t)(j0 + lr) * EMB + 8 * lg;
  const short* opb = Op + (size_t)bbase * 12288;   // head h tile at + h*12288

  #pragma unroll 2
  for (int kt = 0; kt < 24; ++kt) {
    int k = kt * 32 + 8 * lg;
    int h = k / 96, d = k - h * 96;
    const short* o0 = opb + (size_t)h * 12288;
    const short* o1 = o0 + (size_t)512 * 12288;
    bf16x8 pa0 = *(const bf16x8*)(o0 + qrow0 * 96 + d);
    bf16x8 pb0 = *(const bf16x8*)(o1 + qrow0 * 96 + d);
    bf16x8 pa1 = *(const bf16x8*)(o0 + qrow1 * 96 + d);
    bf16x8 pb1 = *(const bf16x8*)(o1 + qrow1 * 96 + d);
    float v0 = il0[h], v1 = il1[h];
    bf16x8 a0, a1;
    #pragma unroll
    for (int e = 0; e < 8; ++e) {
      a0[e] = f2bfh((bf2f(pa0[e]) + bf2f(pb0[e])) * v0);
      a1[e] = f2bfh((bf2f(pa1[e]) + bf2f(pb1[e])) * v1);
    }
    #pragma unroll
    for (int jt = 0; jt < 4; ++jt) {
      bf16x8 bw = *(const bf16x8*)(wp + (size_t)(jt * 16) * EMB + kt * 32);
      acc[0][jt] = __builtin_amdgcn_mfma_f32_16x16x32_bf16(a0, bw, acc[0][jt], 0, 0, 0);
      acc[1][jt] = __builtin_amdgcn_mfma_f32_16x16x32_bf16(a1, bw, acc[1][jt], 0, 0, 0);
    }
  }
  #pragma unroll
  for (int jt = 0; jt < 4; ++jt) {
    float bb = bias[j0 + jt * 16 + lr];
    #pragma unroll
    for (int sub = 0; sub < 2; ++sub) {
      #pragma unroll
      for (int i = 0; i < 4; ++i)
        out[(size_t)(m0 + w * 32 + sub * 16 + 4 * lg + i) * EMB + j0 + jt * 16 + lr]
            = acc[sub][jt][i] + bb;
    }
  }
}

// ---------- plain FC (fallback path, r21 version) ----------
__global__ __launch_bounds__(256) void fc_kernel(const short* __restrict__ Xb,
                                                 const short* __restrict__ Wb,
                                                 const float* __restrict__ bias,
                                                 float* __restrict__ out) {
  int m0 = blockIdx.x * 128, j0 = blockIdx.y * 64;
  int tid = threadIdx.x;
  int w = tid >> 6, lane = tid & 63, lr = lane & 15, lg = lane >> 4;
  f32x4 acc[2][4];
  #pragma unroll
  for (int sub = 0; sub < 2; ++sub)
    #pragma unroll
    for (int jt = 0; jt < 4; ++jt) acc[sub][jt] = (f32x4){0.f, 0.f, 0.f, 0.f};
  const short* xp0 = Xb + (size_t)(m0 + w * 32 + lr) * EMB + 8 * lg;
  const short* xp1 = xp0 + (size_t)16 * EMB;
  const short* wp = Wb + (size_t)(j0 + lr) * EMB + 8 * lg;
  #pragma unroll 2
  for (int kt = 0; kt < 24; ++kt) {
    bf16x8 a0 = *(const bf16x8*)(xp0 + kt * 32);
    bf16x8 a1 = *(const bf16x8*)(xp1 + kt * 32);
    #pragma unroll
    for (int jt = 0; jt < 4; ++jt) {
      bf16x8 bw = *(const bf16x8*)(wp + (size_t)(jt * 16) * EMB + kt * 32);
      acc[0][jt] = __builtin_amdgcn_mfma_f32_16x16x32_bf16(a0, bw, acc[0][jt], 0, 0, 0);
      acc[1][jt] = __builtin_amdgcn_mfma_f32_16x16x32_bf16(a1, bw, acc[1][jt], 0, 0, 0);
    }
  }
  #pragma unroll
  for (int jt = 0; jt < 4; ++jt) {
    float bb = bias[j0 + jt * 16 + lr];
    #pragma unroll
    for (int sub = 0; sub < 2; ++sub) {
      #pragma unroll
      for (int i = 0; i < 4; ++i)
        out[(size_t)(m0 + w * 32 + sub * 16 + 4 * lg + i) * EMB + j0 + jt * 16 + lr]
            = acc[sub][jt][i] + bb;
    }
  }
}

extern "C" void kernel_launch(void* const* d_in, const int* in_sizes, int n_in,
                              void* d_out, int out_size, void* d_ws, size_t ws_size,
                              hipStream_t stream) {
  (void)in_sizes; (void)n_in; (void)out_size;
  const float* V = (const float*)d_in[0];
  const float* K = (const float*)d_in[1];
  const float* Q = (const float*)d_in[2];
  const float* W = (const float*)d_in[3];
  const float* B = (const float*)d_in[4];
  float* out = (float*)d_out;
  // ws (shorts): KVT[12582912] | Wb[589824] | Xb[6291456] | Op bf16 | lp f32
  short* KVT = (short*)d_ws;
  short* Wb  = KVT + 12582912;
  short* Xb  = Wb + 589824;
  size_t base_bytes = (size_t)(12582912 + 589824 + 6291456) * 2;
  size_t part_bytes = (size_t)2 * 512 * 12288 * 2 + (size_t)2 * 512 * 128 * 4;
  prep_kernel<<<2336, 256, 0, stream>>>(K, W, V, KVT, Wb);
  if (ws_size >= base_bytes + part_bytes) {
    short* Op = (short*)((char*)d_ws + base_bytes);
    float* lp = (float*)(Op + (size_t)2 * 512 * 12288);
    attn_kernel<2><<<1024, 128, 0, stream>>>(Q, KVT, Xb, Op, lp);
    fc_fused_kernel<<<dim3(64, 12), 256, 0, stream>>>(Op, lp, Wb, B, out);
  } else {
    attn_kernel<1><<<512, 128, 0, stream>>>(Q, KVT, Xb, nullptr, nullptr);
    fc_kernel<<<dim3(64, 12), 256, 0, stream>>>(Xb, Wb, B, out);
  }
}

// Round 23
// 175.125 us; speedup vs baseline: 1.3004x; 1.0010x over previous
//
#include <hip/hip_runtime.h>
#include <hip/hip_bf16.h>

#define S_LEN 4096
#define EMB 768
#define NHEAD 8
#define HDIM 96

typedef short bf16x8 __attribute__((ext_vector_type(8)));
typedef float f32x4 __attribute__((ext_vector_type(4)));
typedef float f32x16 __attribute__((ext_vector_type(16)));

__device__ __forceinline__ short f2bf(float x) {
  union { float f; unsigned u; } v; v.f = x;
  unsigned r = v.u + 0x7fffu + ((v.u >> 16) & 1u);   // round-to-nearest-even
  return (short)(r >> 16);
}

__device__ __forceinline__ short f2bfh(float x) {
  union { __hip_bfloat16 h; short s; } u;
  u.h = __float2bfloat16(x);
  return u.s;
}

__device__ __forceinline__ float bf2f(short s) {
  union { unsigned u; float f; } v;
  v.u = ((unsigned)(unsigned short)s) << 16;
  return v.f;
}

#define GLOAD_LDS16(gp, lp)                                              \
  __builtin_amdgcn_global_load_lds(                                      \
      (const __attribute__((address_space(1))) unsigned int*)(gp),       \
      (__attribute__((address_space(3))) unsigned int*)(lp), 16, 0, 0)

// ---------- fused prep (byte-identical to r21/r22) ----------
__global__ __launch_bounds__(256) void prep_kernel(const float* __restrict__ K,
                                                   const float* __restrict__ W,
                                                   const float* __restrict__ V,
                                                   short* __restrict__ KVT,
                                                   short* __restrict__ Wb) {
  __shared__ short tlbuf[6656];
  int b = blockIdx.x;
  int tid = threadIdx.x;
  if (b < 288) {
    int t = b * 256 + tid;
    size_t off = (size_t)t * 8;
    float4 a = *(const float4*)(W + off);
    float4 bq = *(const float4*)(W + off + 4);
    bf16x8 r;
    r[0]=f2bf(a.x);  r[1]=f2bf(a.y);  r[2]=f2bf(a.z);  r[3]=f2bf(a.w);
    r[4]=f2bf(bq.x); r[5]=f2bf(bq.y); r[6]=f2bf(bq.z); r[7]=f2bf(bq.w);
    *(bf16x8*)(Wb + off) = r;
    return;
  }
  if (b < 1312) {
    // K tile: direct convert, no LDS, no barriers (source 16B contiguous)
    int bb = b - 288;
    int n = bb >> 9, h = (bb >> 6) & 7, st = bb & 63;
    int s0 = st * 64;
    const float* kp = K + ((size_t)(n * S_LEN + s0)) * EMB + h * HDIM;
    short* KVp = KVT + ((size_t)((n * NHEAD + h) * 64 + st)) * 12288;
    #pragma unroll
    for (int i = 0; i < 3; ++i) {
      int u = i * 256 + tid;
      int c = u >> 7, rem = u & 127;
      int ksub = (rem >> 6) & 1, hi2 = (rem >> 5) & 1, l31 = rem & 31;
      int key = ksub * 32 + l31;
      const float* src = kp + (size_t)key * EMB + c * 16 + hi2 * 8;
      float4 x0 = ((const float4*)src)[0];
      float4 x1 = ((const float4*)src)[1];
      bf16x8 r;
      r[0]=f2bf(x0.x); r[1]=f2bf(x0.y); r[2]=f2bf(x0.z); r[3]=f2bf(x0.w);
      r[4]=f2bf(x1.x); r[5]=f2bf(x1.y); r[6]=f2bf(x1.z); r[7]=f2bf(x1.w);
      *(bf16x8*)(KVp + (size_t)u * 8) = r;
    }
    return;
  }
  // V tile: lane-linear sigma layout (sigma = swap key bits 2<->3)
  int bb = b - 1312;
  int n = bb >> 9, h = (bb >> 6) & 7, st = bb & 63;
  int s0 = st * 64;
  const float* vp = V + ((size_t)(n * S_LEN + s0)) * EMB + h * HDIM;
  #pragma unroll
  for (int k = 0; k < 6; ++k) {
    int idx = k * 256 + tid;
    int fidx = idx * 4;
    int s = fidx / 96, d = fidx % 96;
    float4 a = *(const float4*)(vp + (size_t)s * EMB + d);
    tlbuf[(d + 0) * 68 + s] = f2bf(a.x);
    tlbuf[(d + 1) * 68 + s] = f2bf(a.y);
    tlbuf[(d + 2) * 68 + s] = f2bf(a.z);
    tlbuf[(d + 3) * 68 + s] = f2bf(a.w);
  }
  __syncthreads();
  short* KVp = KVT + ((size_t)((n * NHEAD + h) * 64 + st)) * 12288 + 6144;
  #pragma unroll
  for (int i = 0; i < 3; ++i) {
    int u = i * 256 + tid;
    int slice = u / 192;
    int rem = u - slice * 192;
    int dt = rem >> 6, hi2 = (rem >> 5) & 1, d5 = rem & 31;
    int d = dt * 32 + d5;
    int kb = 16 * slice + 4 * hi2;
    short4 lo = *(const short4*)&tlbuf[d * 68 + kb];
    short4 hi4 = *(const short4*)&tlbuf[d * 68 + kb + 8];
    bf16x8 r;
    r[0]=lo.x; r[1]=lo.y; r[2]=lo.z; r[3]=lo.w;
    r[4]=hi4.x; r[5]=hi4.y; r[6]=hi4.z; r[7]=hi4.w;
    *(bf16x8*)(KVp + (size_t)u * 8) = r;
  }
}

// ---------- flash attention: r20 body + T4-lite counted-vmcnt sync ----------
// Raw s_barrier + hand-counted s_waitcnt replaces __syncthreads (which force-drains
// vmcnt(0) and stalled every iter on the just-issued V prefetch).
// Loop invariant at iter t entry: kbuf = K(t) (all waves), outstanding own loads = V(t).
//   A:  QK from kbuf
//   W1: vmcnt(0)  -- own V(t) done (issued iter t-1 -> ~full-iter latency cover)
//   B1: s_barrier -- cross-wave: V(t) visible; all kbuf reads done (overwrite safe)
//   B:  issue K(t+1) [6 loads] then V(t+1) [6 loads]
//   C:  exp / pack / PV reading vbuf[cur] = V(t)
//   W2: vmcnt(6)  -- 6 oldest (K(t+1)) done; V(t+1) STAYS IN FLIGHT across barrier
//   B2: s_barrier -- kbuf = K(t+1) valid
// vmcnt retires in issue order (m135), so <=6 outstanding => all K done.
template<int NKG>
__global__ __launch_bounds__(128, 2) void attn_kernel(const float* __restrict__ Q,
                                                      const short* __restrict__ KVT,
                                                      short* __restrict__ Xb,
                                                      short* __restrict__ Op,
                                                      float* __restrict__ lp) {
  __shared__ __align__(16) char smem[36864];   // kbuf 12KB @0 | vbuf[2] 12KB @12288
  constexpr int ITERS = S_LEN / NKG / 64;
  int L = blockIdx.x;
  int bb = L & 511;
  int kg = L >> 9;
  int h = bb & 7, j = bb >> 3;
  int n = j >> 5, qt = j & 31;
  int q0 = qt * 128;
  int tid = threadIdx.x;
  int w = tid >> 6, lane = tid & 63, l31 = lane & 31, hi = lane >> 5;

  const float kAdj = 0.14724512f;  // (1/sqrt(96)) * log2(e), folded into Q
  bf16x8 qfa[6], qfb[6];
  #pragma unroll
  for (int sub = 0; sub < 2; ++sub) {
    const float* qp = Q + ((size_t)(n * S_LEN + q0 + w * 64 + sub * 32 + l31)) * EMB
                        + h * HDIM + 8 * hi;
    #pragma unroll
    for (int c = 0; c < 6; ++c) {
      float4 a = *(const float4*)(qp + 16 * c);
      float4 bq = *(const float4*)(qp + 16 * c + 4);
      bf16x8 r;
      r[0]=f2bf(a.x*kAdj);  r[1]=f2bf(a.y*kAdj);  r[2]=f2bf(a.z*kAdj);  r[3]=f2bf(a.w*kAdj);
      r[4]=f2bf(bq.x*kAdj); r[5]=f2bf(bq.y*kAdj); r[6]=f2bf(bq.z*kAdj); r[7]=f2bf(bq.w*kAdj);
      if (sub == 0) qfa[c] = r; else qfb[c] = r;
    }
  }

  const short* gKV = KVT + ((size_t)((n * NHEAD + h) * 64 + kg * ITERS)) * 12288
                        + (size_t)(w * 6) * 512 + lane * 8;
  char* kbuf = smem;
  char* vbuf = smem + 12288;
  char* kdst = kbuf + w * 6144;
  char* vdst0 = vbuf + w * 6144;

  // prologue: stage K(0) + V(0); full drain (loop invariant: V(0) "done")
  #pragma unroll
  for (int i = 0; i < 6; ++i) {
    GLOAD_LDS16(gKV + i * 512, kdst + i * 1024);
    GLOAD_LDS16(gKV + 6144 + i * 512, vdst0 + i * 1024);
  }
  __syncthreads();

  f32x16 oa[3], ob[3];
  #pragma unroll
  for (int dt = 0; dt < 3; ++dt) { oa[dt] = (f32x16){}; ob[dt] = (f32x16){}; }
  float tsa = 0.f, tsb = 0.f;

  int cur = 0;
  #pragma unroll 1
  for (int t = 0; t < ITERS; ++t) {
    // ---- phase A: QK from kbuf (4 independent chains, K read once) ----
    f32x16 s0a = (f32x16){}, s1a = (f32x16){}, s0b = (f32x16){}, s1b = (f32x16){};
    __builtin_amdgcn_s_setprio(1);
    #pragma unroll
    for (int c = 0; c < 6; ++c) {
      bf16x8 kf0 = *(const bf16x8*)(kbuf + c * 2048 + lane * 16);
      bf16x8 kf1 = *(const bf16x8*)(kbuf + c * 2048 + 1024 + lane * 16);
      s0a = __builtin_amdgcn_mfma_f32_32x32x16_bf16(kf0, qfa[c], s0a, 0, 0, 0);
      s0b = __builtin_amdgcn_mfma_f32_32x32x16_bf16(kf0, qfb[c], s0b, 0, 0, 0);
      s1a = __builtin_amdgcn_mfma_f32_32x32x16_bf16(kf1, qfa[c], s1a, 0, 0, 0);
      s1b = __builtin_amdgcn_mfma_f32_32x32x16_bf16(kf1, qfb[c], s1b, 0, 0, 0);
    }
    __builtin_amdgcn_s_setprio(0);

    // ---- W1 + B1: own V(t) complete, then cross-wave sync ----
    asm volatile("s_waitcnt vmcnt(0)" ::: "memory");
    __builtin_amdgcn_sched_barrier(0);
    __builtin_amdgcn_s_barrier();
    __builtin_amdgcn_sched_barrier(0);

    // ---- phase B: issue K(t+1) first, then V(t+1) ----
    if (t < ITERS - 1) {
      const short* src = gKV + (size_t)(t + 1) * 12288;
      char* vd = vbuf + (cur ^ 1) * 12288 + w * 6144;
      #pragma unroll
      for (int i = 0; i < 6; ++i)
        GLOAD_LDS16(src + i * 512, kdst + i * 1024);
      #pragma unroll
      for (int i = 0; i < 6; ++i)
        GLOAD_LDS16(src + 6144 + i * 512, vd + i * 1024);
    }

    // ---- phase C: P = 2^score; pairwise-tree row-sums; pack + PV ----
    #pragma unroll
    for (int r = 0; r < 16; ++r) s0a[r] = __builtin_amdgcn_exp2f(s0a[r]);
    #pragma unroll
    for (int r = 0; r < 16; ++r) s1a[r] = __builtin_amdgcn_exp2f(s1a[r]);
    #pragma unroll
    for (int r = 0; r < 16; ++r) s0b[r] = __builtin_amdgcn_exp2f(s0b[r]);
    #pragma unroll
    for (int r = 0; r < 16; ++r) s1b[r] = __builtin_amdgcn_exp2f(s1b[r]);
    {
      float a0 = (s0a[0]+s0a[1])+(s0a[2]+s0a[3]), a1 = (s0a[4]+s0a[5])+(s0a[6]+s0a[7]);
      float a2 = (s0a[8]+s0a[9])+(s0a[10]+s0a[11]), a3 = (s0a[12]+s0a[13])+(s0a[14]+s0a[15]);
      float b0 = (s1a[0]+s1a[1])+(s1a[2]+s1a[3]), b1 = (s1a[4]+s1a[5])+(s1a[6]+s1a[7]);
      float b2 = (s1a[8]+s1a[9])+(s1a[10]+s1a[11]), b3 = (s1a[12]+s1a[13])+(s1a[14]+s1a[15]);
      tsa += ((a0+a1)+(a2+a3)) + ((b0+b1)+(b2+b3));
      float c0 = (s0b[0]+s0b[1])+(s0b[2]+s0b[3]), c1 = (s0b[4]+s0b[5])+(s0b[6]+s0b[7]);
      float c2 = (s0b[8]+s0b[9])+(s0b[10]+s0b[11]), c3 = (s0b[12]+s0b[13])+(s0b[14]+s0b[15]);
      float d0_ = (s1b[0]+s1b[1])+(s1b[2]+s1b[3]), d1_ = (s1b[4]+s1b[5])+(s1b[6]+s1b[7]);
      float d2_ = (s1b[8]+s1b[9])+(s1b[10]+s1b[11]), d3_ = (s1b[12]+s1b[13])+(s1b[14]+s1b[15]);
      tsb += ((c0+c1)+(c2+c3)) + ((d0_+d1_)+(d2_+d3_));
    }

    const char* vbl = vbuf + cur * 12288;
    #pragma unroll
    for (int ksub = 0; ksub < 2; ++ksub) {
      const f32x16& sa = ksub ? s1a : s0a;
      const f32x16& sb = ksub ? s1b : s0b;
      #pragma unroll
      for (int ks = 0; ks < 2; ++ks) {
        unsigned a0, a1, a2, a3, b0, b1, b2, b3;
        asm("v_cvt_pk_bf16_f32 %0, %1, %2" : "=v"(a0) : "v"(sa[8*ks+0]), "v"(sa[8*ks+1]));
        asm("v_cvt_pk_bf16_f32 %0, %1, %2" : "=v"(a1) : "v"(sa[8*ks+2]), "v"(sa[8*ks+3]));
        asm("v_cvt_pk_bf16_f32 %0, %1, %2" : "=v"(a2) : "v"(sa[8*ks+4]), "v"(sa[8*ks+5]));
        asm("v_cvt_pk_bf16_f32 %0, %1, %2" : "=v"(a3) : "v"(sa[8*ks+6]), "v"(sa[8*ks+7]));
        asm("v_cvt_pk_bf16_f32 %0, %1, %2" : "=v"(b0) : "v"(sb[8*ks+0]), "v"(sb[8*ks+1]));
        asm("v_cvt_pk_bf16_f32 %0, %1, %2" : "=v"(b1) : "v"(sb[8*ks+2]), "v"(sb[8*ks+3]));
        asm("v_cvt_pk_bf16_f32 %0, %1, %2" : "=v"(b2) : "v"(sb[8*ks+4]), "v"(sb[8*ks+5]));
        asm("v_cvt_pk_bf16_f32 %0, %1, %2" : "=v"(b3) : "v"(sb[8*ks+6]), "v"(sb[8*ks+7]));
        union { unsigned u[4]; bf16x8 v; } pa, pb;
        pa.u[0] = a0; pa.u[1] = a1; pa.u[2] = a2; pa.u[3] = a3;
        pb.u[0] = b0; pb.u[1] = b1; pb.u[2] = b2; pb.u[3] = b3;
        int slice = 2 * ksub + ks;
        __builtin_amdgcn_s_setprio(1);
        #pragma unroll
        for (int dt = 0; dt < 3; ++dt) {
          bf16x8 vf = *(const bf16x8*)(vbl + (slice * 3 + dt) * 1024 + hi * 512 + l31 * 16);
          oa[dt] = __builtin_amdgcn_mfma_f32_32x32x16_bf16(pa.v, vf, oa[dt], 0, 0, 0);
          ob[dt] = __builtin_amdgcn_mfma_f32_32x32x16_bf16(pb.v, vf, ob[dt], 0, 0, 0);
        }
        __builtin_amdgcn_s_setprio(0);
      }
    }

    // ---- W2 + B2: 6 oldest (K(t+1)) done; V(t+1) stays in flight across barrier ----
    asm volatile("s_waitcnt vmcnt(6)" ::: "memory");
    __builtin_amdgcn_sched_barrier(0);
    __builtin_amdgcn_s_barrier();
    __builtin_amdgcn_sched_barrier(0);
    cur ^= 1;
  }

  float la = tsa + __shfl_xor(tsa, 32, 64);
  float lb = tsb + __shfl_xor(tsb, 32, 64);

  if constexpr (NKG > 1) {
    short* op = Op + (size_t)L * 12288;
    #pragma unroll
    for (int p = 0; p < 4; ++p) {
      #pragma unroll
      for (int jj = 0; jj < 4; ++jj) {
        int qra = w * 64 + 8 * p + 4 * hi + jj;
        op[(size_t)qra * 96 + l31]      = f2bfh(oa[0][4*p+jj]);
        op[(size_t)qra * 96 + 32 + l31] = f2bfh(oa[1][4*p+jj]);
        op[(size_t)qra * 96 + 64 + l31] = f2bfh(oa[2][4*p+jj]);
        int qrb = qra + 32;
        op[(size_t)qrb * 96 + l31]      = f2bfh(ob[0][4*p+jj]);
        op[(size_t)qrb * 96 + 32 + l31] = f2bfh(ob[1][4*p+jj]);
        op[(size_t)qrb * 96 + 64 + l31] = f2bfh(ob[2][4*p+jj]);
      }
    }
    if (hi == 0) {
      lp[(size_t)L * 128 + w * 64 + l31] = la;
      lp[(size_t)L * 128 + w * 64 + 32 + l31] = lb;
    }
  } else {
    __syncthreads();
    float* bcf = (float*)smem;
    if (hi == 0) {
      bcf[w * 64 + l31] = 1.0f / la;
      bcf[w * 64 + 32 + l31] = 1.0f / lb;
    }
    __syncthreads();
    #pragma unroll
    for (int p = 0; p < 4; ++p) {
      #pragma unroll
      for (int jj = 0; jj < 4; ++jj) {
        int qr = 8 * p + 4 * hi + jj;
        float iva = bcf[w * 64 + qr];
        float ivb = bcf[w * 64 + 32 + qr];
        short* xpa = Xb + ((size_t)(n * S_LEN + q0 + w * 64 + qr)) * EMB + h * HDIM + l31;
        xpa[0]  = f2bfh(oa[0][4*p+jj] * iva);
        xpa[32] = f2bfh(oa[1][4*p+jj] * iva);
        xpa[64] = f2bfh(oa[2][4*p+jj] * iva);
        short* xpb = xpa + (size_t)32 * EMB;
        xpb[0]  = f2bfh(ob[0][4*p+jj] * ivb);
        xpb[32] = f2bfh(ob[1][4*p+jj] * ivb);
        xpb[64] = f2bfh(ob[2][4*p+jj] * ivb);
      }
    }
  }
}

// ---------- fused FC (byte-identical to r22) ----------
__global__ __launch_bounds__(256) void fc_fused_kernel(const short* __restrict__ Op,
                                                       const float* __restrict__ lp,
                                                       const short* __restrict__ Wb,
                                                       const float* __restrict__ bias,
                                                       float* __restrict__ out) {
  int m0 = blockIdx.x * 128, j0 = blockIdx.y * 64;
  int tid = threadIdx.x;
  int w = tid >> 6, lane = tid & 63, lr = lane & 15, lg = lane >> 4;
  int n = m0 >> 12, qt = (m0 & 4095) >> 7;
  int bbase = (n * 32 + qt) * 8;
  int qrow0 = w * 32 + lr, qrow1 = qrow0 + 16;

  float il0[8], il1[8];
  #pragma unroll
  for (int h = 0; h < 8; ++h) {
    size_t L0 = (size_t)(bbase + h), L1 = L0 + 512;
    il0[h] = 1.0f / (lp[L0 * 128 + qrow0] + lp[L1 * 128 + qrow0]);
    il1[h] = 1.0f / (lp[L0 * 128 + qrow1] + lp[L1 * 128 + qrow1]);
  }

  f32x4 acc[2][4];
  #pragma unroll
  for (int sub = 0; sub < 2; ++sub)
    #pragma unroll
    for (int jt = 0; jt < 4; ++jt) acc[sub][jt] = (f32x4){0.f, 0.f, 0.f, 0.f};

  const short* wp = Wb + (size_t)(j0 + lr) * EMB + 8 * lg;
  const short* opb = Op + (size_t)bbase * 12288;

  #pragma unroll 2
  for (int kt = 0; kt < 24; ++kt) {
    int k = kt * 32 + 8 * lg;
    int h = k / 96, d = k - h * 96;
    const short* o0 = opb + (size_t)h * 12288;
    const short* o1 = o0 + (size_t)512 * 12288;
    bf16x8 pa0 = *(const bf16x8*)(o0 + qrow0 * 96 + d);
    bf16x8 pb0 = *(const bf16x8*)(o1 + qrow0 * 96 + d);
    bf16x8 pa1 = *(const bf16x8*)(o0 + qrow1 * 96 + d);
    bf16x8 pb1 = *(const bf16x8*)(o1 + qrow1 * 96 + d);
    float v0 = il0[h], v1 = il1[h];
    bf16x8 a0, a1;
    #pragma unroll
    for (int e = 0; e < 8; ++e) {
      a0[e] = f2bfh((bf2f(pa0[e]) + bf2f(pb0[e])) * v0);
      a1[e] = f2bfh((bf2f(pa1[e]) + bf2f(pb1[e])) * v1);
    }
    #pragma unroll
    for (int jt = 0; jt < 4; ++jt) {
      bf16x8 bw = *(const bf16x8*)(wp + (size_t)(jt * 16) * EMB + kt * 32);
      acc[0][jt] = __builtin_amdgcn_mfma_f32_16x16x32_bf16(a0, bw, acc[0][jt], 0, 0, 0);
      acc[1][jt] = __builtin_amdgcn_mfma_f32_16x16x32_bf16(a1, bw, acc[1][jt], 0, 0, 0);
    }
  }
  #pragma unroll
  for (int jt = 0; jt < 4; ++jt) {
    float bb = bias[j0 + jt * 16 + lr];
    #pragma unroll
    for (int sub = 0; sub < 2; ++sub) {
      #pragma unroll
      for (int i = 0; i < 4; ++i)
        out[(size_t)(m0 + w * 32 + sub * 16 + 4 * lg + i) * EMB + j0 + jt * 16 + lr]
            = acc[sub][jt][i] + bb;
    }
  }
}

// ---------- plain FC (fallback path) ----------
__global__ __launch_bounds__(256) void fc_kernel(const short* __restrict__ Xb,
                                                 const short* __restrict__ Wb,
                                                 const float* __restrict__ bias,
                                                 float* __restrict__ out) {
  int m0 = blockIdx.x * 128, j0 = blockIdx.y * 64;
  int tid = threadIdx.x;
  int w = tid >> 6, lane = tid & 63, lr = lane & 15, lg = lane >> 4;
  f32x4 acc[2][4];
  #pragma unroll
  for (int sub = 0; sub < 2; ++sub)
    #pragma unroll
    for (int jt = 0; jt < 4; ++jt) acc[sub][jt] = (f32x4){0.f, 0.f, 0.f, 0.f};
  const short* xp0 = Xb + (size_t)(m0 + w * 32 + lr) * EMB + 8 * lg;
  const short* xp1 = xp0 + (size_t)16 * EMB;
  const short* wp = Wb + (size_t)(j0 + lr) * EMB + 8 * lg;
  #pragma unroll 2
  for (int kt = 0; kt < 24; ++kt) {
    bf16x8 a0 = *(const bf16x8*)(xp0 + kt * 32);
    bf16x8 a1 = *(const bf16x8*)(xp1 + kt * 32);
    #pragma unroll
    for (int jt = 0; jt < 4; ++jt) {
      bf16x8 bw = *(const bf16x8*)(wp + (size_t)(jt * 16) * EMB + kt * 32);
      acc[0][jt] = __builtin_amdgcn_mfma_f32_16x16x32_bf16(a0, bw, acc[0][jt], 0, 0, 0);
      acc[1][jt] = __builtin_amdgcn_mfma_f32_16x16x32_bf16(a1, bw, acc[1][jt], 0, 0, 0);
    }
  }
  #pragma unroll
  for (int jt = 0; jt < 4; ++jt) {
    float bb = bias[j0 + jt * 16 + lr];
    #pragma unroll
    for (int sub = 0; sub < 2; ++sub) {
      #pragma unroll
      for (int i = 0; i < 4; ++i)
        out[(size_t)(m0 + w * 32 + sub * 16 + 4 * lg + i) * EMB + j0 + jt * 16 + lr]
            = acc[sub][jt][i] + bb;
    }
  }
}

extern "C" void kernel_launch(void* const* d_in, const int* in_sizes, int n_in,
                              void* d_out, int out_size, void* d_ws, size_t ws_size,
                              hipStream_t stream) {
  (void)in_sizes; (void)n_in; (void)out_size;
  const float* V = (const float*)d_in[0];
  const float* K = (const float*)d_in[1];
  const float* Q = (const float*)d_in[2];
  const float* W = (const float*)d_in[3];
  const float* B = (const float*)d_in[4];
  float* out = (float*)d_out;
  // ws (shorts): KVT[12582912] | Wb[589824] | Xb[6291456] | Op bf16 | lp f32
  short* KVT = (short*)d_ws;
  short* Wb  = KVT + 12582912;
  short* Xb  = Wb + 589824;
  size_t base_bytes = (size_t)(12582912 + 589824 + 6291456) * 2;
  size_t part_bytes = (size_t)2 * 512 * 12288 * 2 + (size_t)2 * 512 * 128 * 4;
  prep_kernel<<<2336, 256, 0, stream>>>(K, W, V, KVT, Wb);
  if (ws_size >= base_bytes + part_bytes) {
    short* Op = (short*)((char*)d_ws + base_bytes);
    float* lp = (float*)(Op + (size_t)2 * 512 * 12288);
    attn_kernel<2><<<1024, 128, 0, stream>>>(Q, KVT, Xb, Op, lp);
    fc_fused_kernel<<<dim3(64, 12), 256, 0, stream>>>(Op, lp, Wb, B, out);
  } else {
    attn_kernel<1><<<512, 128, 0, stream>>>(Q, KVT, Xb, nullptr, nullptr);
    fc_kernel<<<dim3(64, 12), 256, 0, stream>>>(Xb, Wb, B, out);
  }
}